// Round 1
// baseline (1498.780 us; speedup 1.0000x reference)
//
#include <hip/hip_runtime.h>
#include <hip/hip_bf16.h>
#include <cstdint>
#include <cstddef>

#define BB 256
#define NN 128
#define LL 2048
#define DD 64
#define KS 23
#define PAD 11
#define EPSF 1e-6f

__device__ __forceinline__ float bf2f(uint32_t u) {
  union { uint32_t i; float f; } c; c.i = u << 16; return c.f;
}
__device__ __forceinline__ uint16_t f2bf(float f) {
  union { float f; uint32_t i; } c; c.f = f;
  uint32_t i = c.i;
  return (uint16_t)((i + 0x7fffu + ((i >> 16) & 1u)) >> 16);
}

// ---------------------------------------------------------------- GNN ------
// One block per b. xs,hs in LDS (64KB). W row per-lane in registers.
__global__ __launch_bounds__(256) void gnn_kernel(
    const int* __restrict__ atoms, const float* __restrict__ atoms_mask,
    const float* __restrict__ adj, const float* __restrict__ emb_fp,
    const float* __restrict__ W_gnn, const float* __restrict__ b_gnn,
    float* __restrict__ compound)
{
  __shared__ float xs[NN][DD];
  __shared__ float hs[NN][DD];
  const int b = blockIdx.x;
  const int tid = threadIdx.x;
  const int e = tid & 63;
  const int g = __builtin_amdgcn_readfirstlane(tid >> 6);

  // xs = emb_fp[atoms[b]]
  for (int idx = tid; idx < NN * DD; idx += 256) {
    int n = idx >> 6, d = idx & 63;
    int a = atoms[b * NN + n];
    xs[n][d] = emb_fp[(size_t)a * DD + d];
  }

  float wreg[DD];
  for (int layer = 0; layer < 3; ++layer) {
    const float* wrow = W_gnn + (size_t)layer * DD * DD + (size_t)e * DD;
    #pragma unroll
    for (int d4 = 0; d4 < DD / 4; ++d4) {
      float4 w = ((const float4*)wrow)[d4];
      wreg[4 * d4 + 0] = w.x; wreg[4 * d4 + 1] = w.y;
      wreg[4 * d4 + 2] = w.z; wreg[4 * d4 + 3] = w.w;
    }
    const float breg = b_gnn[layer * DD + e];
    __syncthreads();
    // hs = relu(xs @ W^T + b)   (lane = output e, 32 rows per group)
    for (int n = g * 32; n < g * 32 + 32; ++n) {
      float acc = breg;
      #pragma unroll
      for (int d4 = 0; d4 < DD / 4; ++d4) {
        float4 x = ((const float4*)&xs[n][0])[d4];
        acc = fmaf(x.x, wreg[4 * d4 + 0], acc);
        acc = fmaf(x.y, wreg[4 * d4 + 1], acc);
        acc = fmaf(x.z, wreg[4 * d4 + 2], acc);
        acc = fmaf(x.w, wreg[4 * d4 + 3], acc);
      }
      hs[n][e] = fmaxf(acc, 0.f);
    }
    __syncthreads();
    // xs += adj @ hs   (lane = d, adj rows are wave-uniform scalar loads)
    const float* adjb = adj + (size_t)b * NN * NN;
    for (int nb = 0; nb < 8; ++nb) {
      int n0 = g * 32 + nb * 4;
      float a0 = 0.f, a1 = 0.f, a2 = 0.f, a3 = 0.f;
      const float* r0 = adjb + (size_t)(n0 + 0) * NN;
      const float* r1 = adjb + (size_t)(n0 + 1) * NN;
      const float* r2 = adjb + (size_t)(n0 + 2) * NN;
      const float* r3 = adjb + (size_t)(n0 + 3) * NN;
      #pragma unroll 8
      for (int m = 0; m < NN; ++m) {
        float h = hs[m][e];
        a0 = fmaf(r0[m], h, a0);
        a1 = fmaf(r1[m], h, a1);
        a2 = fmaf(r2[m], h, a2);
        a3 = fmaf(r3[m], h, a3);
      }
      xs[n0 + 0][e] += a0;
      xs[n0 + 1][e] += a1;
      xs[n0 + 2][e] += a2;
      xs[n0 + 3][e] += a3;
    }
    __syncthreads();
  }
  // compound = masked mean over atoms
  if (tid < 64) {
    float s = 0.f, den = 0.f;
    for (int n = 0; n < NN; ++n) {
      float m = atoms_mask[b * NN + n];
      s = fmaf(xs[n][tid], m, s);
      den += m;
    }
    compound[b * DD + tid] = s / (den + EPSF);
  }
}

// ------------------------------------------------------------- gather ------
// ps0[b,l,:] = bf16(emb_word[amino[b,l],:])  — 8 elems/thread
__global__ __launch_bounds__(256) void gather_kernel(
    const int* __restrict__ amino, const float* __restrict__ emb_word,
    uint16_t* __restrict__ ps)
{
  int gid = blockIdx.x * 256 + threadIdx.x;
  int row = gid >> 3, c8 = gid & 7;
  int a = amino[row];
  const float* src = emb_word + (size_t)a * DD + c8 * 8;
  float4 f0 = ((const float4*)src)[0];
  float4 f1 = ((const float4*)src)[1];
  union { uint4 u; uint16_t h[8]; } pk;
  pk.h[0] = f2bf(f0.x); pk.h[1] = f2bf(f0.y);
  pk.h[2] = f2bf(f0.z); pk.h[3] = f2bf(f0.w);
  pk.h[4] = f2bf(f1.x); pk.h[5] = f2bf(f1.y);
  pk.h[6] = f2bf(f1.z); pk.h[7] = f2bf(f1.w);
  *(uint4*)(ps + (size_t)row * DD + c8 * 8) = pk.u;
}

// ---------------------------------------------------------------- conv -----
// 23x23 conv over (L,D) plane, zero padded. Block = 64 l-rows of one b.
// LDS tile: 86 rows x 88 (data at cols PAD..PAD+63, halo zeroed).
// Thread: fixed d, 16 l-outputs. Per j: 38-col register stage -> 368 FMAs.
#define TROWS 86
#define TROW  88

__global__ __launch_bounds__(256) void conv_kernel(
    const uint16_t* __restrict__ in, uint16_t* __restrict__ out,
    const float* __restrict__ conv_k, const float* __restrict__ conv_b,
    int layer)
{
  __shared__ float tile[TROWS * TROW];
  __shared__ float kern[KS * KS];
  const int tid = threadIdx.x;
  const int l0 = blockIdx.x * 64;
  const int b  = blockIdx.y;

  for (int i = tid; i < KS * KS; i += 256) kern[i] = conv_k[layer * KS * KS + i];
  for (int i = tid; i < TROWS * TROW / 4; i += 256)
    ((float4*)tile)[i] = make_float4(0.f, 0.f, 0.f, 0.f);
  __syncthreads();

  const uint16_t* inb = in + (size_t)b * LL * DD;
  for (int i = tid; i < TROWS * 8; i += 256) {
    int r = i >> 3, c8 = i & 7;
    int gl = l0 - PAD + r;
    if (gl >= 0 && gl < LL) {
      uint4 v = *(const uint4*)(inb + (size_t)gl * DD + c8 * 8);
      float* dst = tile + r * TROW + PAD + c8 * 8;
      dst[0] = bf2f(v.x & 0xffffu); dst[1] = bf2f(v.x >> 16);
      dst[2] = bf2f(v.y & 0xffffu); dst[3] = bf2f(v.y >> 16);
      dst[4] = bf2f(v.z & 0xffffu); dst[5] = bf2f(v.z >> 16);
      dst[6] = bf2f(v.w & 0xffffu); dst[7] = bf2f(v.w >> 16);
    }
  }
  __syncthreads();

  const int d = tid & 63;
  const int g = __builtin_amdgcn_readfirstlane(tid >> 6);
  const int rbase = g * 16;
  float acc[16];
  #pragma unroll
  for (int t = 0; t < 16; ++t) acc[t] = 0.f;

  const float* tcol = tile + rbase * TROW + d;  // read col = d + j  (in [0,85])
  #pragma unroll 1
  for (int j = 0; j < KS; ++j) {
    float col[38];
    #pragma unroll
    for (int r = 0; r < 38; ++r) col[r] = tcol[r * TROW + j];
    #pragma unroll
    for (int i2 = 0; i2 < KS; ++i2) {
      float kv = kern[i2 * KS + j];
      #pragma unroll
      for (int t = 0; t < 16; ++t) acc[t] = fmaf(col[t + i2], kv, acc[t]);
    }
  }
  const float bias = conv_b[layer];
  uint16_t* outb = out + ((size_t)b * LL + l0 + rbase) * DD + d;
  #pragma unroll
  for (int t = 0; t < 16; ++t)
    outb[(size_t)t * DD] = f2bf(fmaxf(acc[t] + bias, 0.f));
}

// ------------------------------------------------- attention + FC head -----
// One block per b. Streams 64-row ps tiles; W_att row per-lane in registers.
#define PTS 68
#define HTS 69

__global__ __launch_bounds__(256) void attn_out_kernel(
    const uint16_t* __restrict__ ps, const float* __restrict__ amino_mask,
    const float* __restrict__ compound, const float* __restrict__ W_att,
    const float* __restrict__ b_att, const float* __restrict__ W_out,
    const float* __restrict__ b_out, const float* __restrict__ W_int,
    const float* __restrict__ b_int, float* __restrict__ outp)
{
  __shared__ float pt[64 * PTS];
  __shared__ float ht[64 * HTS];
  __shared__ float cvec[64];
  __shared__ float hvec[64];
  __shared__ float wvec[64];
  __shared__ float pacc_s[4][64];
  __shared__ float msum_s[64];
  __shared__ float cat[128];
  __shared__ float cat2[128];

  const int b = blockIdx.x;
  const int tid = threadIdx.x;
  const int e = tid & 63;
  const int g = __builtin_amdgcn_readfirstlane(tid >> 6);

  float wreg[64];
  const float* wrow = W_att + (size_t)e * DD;
  #pragma unroll
  for (int d4 = 0; d4 < 16; ++d4) {
    float4 w = ((const float4*)wrow)[d4];
    wreg[4 * d4 + 0] = w.x; wreg[4 * d4 + 1] = w.y;
    wreg[4 * d4 + 2] = w.z; wreg[4 * d4 + 3] = w.w;
  }
  const float breg = b_att[e];
  if (tid < 64) cvec[tid] = compound[b * DD + tid];
  __syncthreads();

  // h = relu(W_att @ compound + b_att)
  if (tid < 64) {
    float a = breg;
    #pragma unroll
    for (int d4 = 0; d4 < 16; ++d4) {
      float4 c = ((const float4*)cvec)[d4];
      a = fmaf(c.x, wreg[4 * d4 + 0], a);
      a = fmaf(c.y, wreg[4 * d4 + 1], a);
      a = fmaf(c.z, wreg[4 * d4 + 2], a);
      a = fmaf(c.w, wreg[4 * d4 + 3], a);
    }
    hvec[tid] = fmaxf(a, 0.f);
  }

  float pacc = 0.f;
  float macc = 0.f;
  const uint16_t* psb = ps + (size_t)b * LL * DD;
  const float* pmb = amino_mask + (size_t)b * LL;

  for (int t0 = 0; t0 < LL; t0 += 64) {
    __syncthreads();
    // stage ps tile (bf16 -> f32)
    for (int i = tid; i < 64 * 8; i += 256) {
      int r = i >> 3, c8 = i & 7;
      uint4 v = *(const uint4*)(psb + (size_t)(t0 + r) * DD + c8 * 8);
      float* dst = pt + r * PTS + c8 * 8;
      dst[0] = bf2f(v.x & 0xffffu); dst[1] = bf2f(v.x >> 16);
      dst[2] = bf2f(v.y & 0xffffu); dst[3] = bf2f(v.y >> 16);
      dst[4] = bf2f(v.z & 0xffffu); dst[5] = bf2f(v.z >> 16);
      dst[6] = bf2f(v.w & 0xffffu); dst[7] = bf2f(v.w >> 16);
    }
    if (tid < 64) macc += pmb[t0 + tid];
    __syncthreads();
    // hs = relu(ps @ W_att^T + b) * mask
    for (int rr = g * 16; rr < g * 16 + 16; ++rr) {
      float a = breg;
      #pragma unroll
      for (int d4 = 0; d4 < 16; ++d4) {
        float4 x = ((const float4*)(pt + rr * PTS))[d4];
        a = fmaf(x.x, wreg[4 * d4 + 0], a);
        a = fmaf(x.y, wreg[4 * d4 + 1], a);
        a = fmaf(x.z, wreg[4 * d4 + 2], a);
        a = fmaf(x.w, wreg[4 * d4 + 3], a);
      }
      float pm = pmb[t0 + rr];
      ht[rr * HTS + e] = fmaxf(a, 0.f) * pm;
    }
    __syncthreads();
    // weights = tanh(h . hs_row)
    if (tid < 64) {
      float a = 0.f;
      #pragma unroll 8
      for (int dd = 0; dd < 64; ++dd) a = fmaf(ht[tid * HTS + dd], hvec[dd], a);
      wvec[tid] = tanhf(a);
    }
    __syncthreads();
    // protein partial: sum_l w[l] * hs[l][e]
    #pragma unroll
    for (int k = 0; k < 16; ++k) {
      int rr = g + 4 * k;
      pacc = fmaf(wvec[rr], ht[rr * HTS + e], pacc);
    }
  }
  pacc_s[g][e] = pacc;
  if (tid < 64) msum_s[tid] = macc;
  __syncthreads();
  if (tid < 64) {
    float p = pacc_s[0][tid] + pacc_s[1][tid] + pacc_s[2][tid] + pacc_s[3][tid];
    float den = 0.f;
    #pragma unroll 8
    for (int i = 0; i < 64; ++i) den += msum_s[i];
    cat[tid] = cvec[tid];
    cat[64 + tid] = p / (den + EPSF);
  }
  __syncthreads();
  // FC head
  if (tid < 128) {
    float a = b_out[tid];
    const float* wr = W_out + (size_t)tid * 128;
    #pragma unroll 8
    for (int dd = 0; dd < 128; ++dd) a = fmaf(wr[dd], cat[dd], a);
    cat2[tid] = fmaxf(a, 0.f);
  }
  __syncthreads();
  if (tid < 128) {
    float a = b_out[128 + tid];
    const float* wr = W_out + 128 * 128 + (size_t)tid * 128;
    #pragma unroll 8
    for (int dd = 0; dd < 128; ++dd) a = fmaf(wr[dd], cat2[dd], a);
    cat[tid] = fmaxf(a, 0.f);
  }
  __syncthreads();
  if (tid < 2) {
    float a = b_int[tid];
    const float* wr = W_int + (size_t)tid * 128;
    #pragma unroll 8
    for (int dd = 0; dd < 128; ++dd) a = fmaf(wr[dd], cat[dd], a);
    outp[b * 2 + tid] = a;
  }
}

// -------------------------------------------------------------- launch -----
extern "C" void kernel_launch(void* const* d_in, const int* in_sizes, int n_in,
                              void* d_out, int out_size, void* d_ws, size_t ws_size,
                              hipStream_t stream) {
  const int*   atoms      = (const int*)d_in[0];
  const float* atoms_mask = (const float*)d_in[1];
  const float* adjacency  = (const float*)d_in[2];
  const int*   amino      = (const int*)d_in[3];
  const float* amino_mask = (const float*)d_in[4];
  const float* emb_fp     = (const float*)d_in[5];
  const float* emb_word   = (const float*)d_in[6];
  const float* W_gnn      = (const float*)d_in[7];
  const float* b_gnn      = (const float*)d_in[8];
  const float* conv_k     = (const float*)d_in[9];
  const float* conv_b     = (const float*)d_in[10];
  const float* W_att      = (const float*)d_in[11];
  const float* b_att      = (const float*)d_in[12];
  const float* W_out      = (const float*)d_in[13];
  const float* b_out      = (const float*)d_in[14];
  const float* W_int      = (const float*)d_in[15];
  const float* b_int      = (const float*)d_in[16];
  float* out = (float*)d_out;

  char* ws = (char*)d_ws;
  float* compound = (float*)ws;                               // 64 KB
  uint16_t* ps_a = (uint16_t*)(ws + 65536);                   // 64 MB (bf16)
  uint16_t* ps_b = (uint16_t*)(ws + 65536 + (size_t)BB * LL * DD * 2);

  gnn_kernel<<<BB, 256, 0, stream>>>(atoms, atoms_mask, adjacency, emb_fp,
                                     W_gnn, b_gnn, compound);
  gather_kernel<<<(BB * LL * DD / 8) / 256, 256, 0, stream>>>(amino, emb_word, ps_a);
  conv_kernel<<<dim3(LL / 64, BB), 256, 0, stream>>>(ps_a, ps_b, conv_k, conv_b, 0);
  conv_kernel<<<dim3(LL / 64, BB), 256, 0, stream>>>(ps_b, ps_a, conv_k, conv_b, 1);
  conv_kernel<<<dim3(LL / 64, BB), 256, 0, stream>>>(ps_a, ps_b, conv_k, conv_b, 2);
  attn_out_kernel<<<BB, 256, 0, stream>>>(ps_b, amino_mask, compound, W_att,
                                          b_att, W_out, b_out, W_int, b_int, out);
}

// Round 2
// 722.575 us; speedup vs baseline: 2.0742x; 2.0742x over previous
//
#include <hip/hip_runtime.h>
#include <hip/hip_bf16.h>
#include <cstdint>
#include <cstddef>

#define BB 256
#define NN 128
#define LL 2048
#define DD 64
#define KS 23
#define PAD 11
#define EPSF 1e-6f

typedef __bf16 v8bf __attribute__((ext_vector_type(8)));
typedef float v4f __attribute__((ext_vector_type(4)));

__device__ __forceinline__ float bf2f(uint32_t u) {
  union { uint32_t i; float f; } c; c.i = u << 16; return c.f;
}
__device__ __forceinline__ uint16_t f2bf(float f) {
  union { float f; uint32_t i; } c; c.f = f;
  uint32_t i = c.i;
  return (uint16_t)((i + 0x7fffu + ((i >> 16) & 1u)) >> 16);
}

// ---------------------------------------------------------------- GNN ------
__global__ __launch_bounds__(256) void gnn_kernel(
    const int* __restrict__ atoms, const float* __restrict__ atoms_mask,
    const float* __restrict__ adj, const float* __restrict__ emb_fp,
    const float* __restrict__ W_gnn, const float* __restrict__ b_gnn,
    float* __restrict__ compound)
{
  __shared__ float xs[NN][DD];
  __shared__ float hs[NN][DD];
  const int b = blockIdx.x;
  const int tid = threadIdx.x;
  const int e = tid & 63;
  const int g = __builtin_amdgcn_readfirstlane(tid >> 6);

  for (int idx = tid; idx < NN * DD; idx += 256) {
    int n = idx >> 6, d = idx & 63;
    int a = atoms[b * NN + n];
    xs[n][d] = emb_fp[(size_t)a * DD + d];
  }

  float wreg[DD];
  for (int layer = 0; layer < 3; ++layer) {
    const float* wrow = W_gnn + (size_t)layer * DD * DD + (size_t)e * DD;
    #pragma unroll
    for (int d4 = 0; d4 < DD / 4; ++d4) {
      float4 w = ((const float4*)wrow)[d4];
      wreg[4 * d4 + 0] = w.x; wreg[4 * d4 + 1] = w.y;
      wreg[4 * d4 + 2] = w.z; wreg[4 * d4 + 3] = w.w;
    }
    const float breg = b_gnn[layer * DD + e];
    __syncthreads();
    for (int n = g * 32; n < g * 32 + 32; ++n) {
      float acc = breg;
      #pragma unroll
      for (int d4 = 0; d4 < DD / 4; ++d4) {
        float4 x = ((const float4*)&xs[n][0])[d4];
        acc = fmaf(x.x, wreg[4 * d4 + 0], acc);
        acc = fmaf(x.y, wreg[4 * d4 + 1], acc);
        acc = fmaf(x.z, wreg[4 * d4 + 2], acc);
        acc = fmaf(x.w, wreg[4 * d4 + 3], acc);
      }
      hs[n][e] = fmaxf(acc, 0.f);
    }
    __syncthreads();
    const float* adjb = adj + (size_t)b * NN * NN;
    for (int nb = 0; nb < 8; ++nb) {
      int n0 = g * 32 + nb * 4;
      float a0 = 0.f, a1 = 0.f, a2 = 0.f, a3 = 0.f;
      const float* r0 = adjb + (size_t)(n0 + 0) * NN;
      const float* r1 = adjb + (size_t)(n0 + 1) * NN;
      const float* r2 = adjb + (size_t)(n0 + 2) * NN;
      const float* r3 = adjb + (size_t)(n0 + 3) * NN;
      #pragma unroll 8
      for (int m = 0; m < NN; ++m) {
        float h = hs[m][e];
        a0 = fmaf(r0[m], h, a0);
        a1 = fmaf(r1[m], h, a1);
        a2 = fmaf(r2[m], h, a2);
        a3 = fmaf(r3[m], h, a3);
      }
      xs[n0 + 0][e] += a0;
      xs[n0 + 1][e] += a1;
      xs[n0 + 2][e] += a2;
      xs[n0 + 3][e] += a3;
    }
    __syncthreads();
  }
  if (tid < 64) {
    float s = 0.f, den = 0.f;
    for (int n = 0; n < NN; ++n) {
      float m = atoms_mask[b * NN + n];
      s = fmaf(xs[n][tid], m, s);
      den += m;
    }
    compound[b * DD + tid] = s / (den + EPSF);
  }
}

// ------------------------------------------------------------- gather ------
__global__ __launch_bounds__(256) void gather_kernel(
    const int* __restrict__ amino, const float* __restrict__ emb_word,
    uint16_t* __restrict__ ps)
{
  int gid = blockIdx.x * 256 + threadIdx.x;
  int row = gid >> 3, c8 = gid & 7;
  int a = amino[row];
  const float* src = emb_word + (size_t)a * DD + c8 * 8;
  float4 f0 = ((const float4*)src)[0];
  float4 f1 = ((const float4*)src)[1];
  union { uint4 u; uint16_t h[8]; } pk;
  pk.h[0] = f2bf(f0.x); pk.h[1] = f2bf(f0.y);
  pk.h[2] = f2bf(f0.z); pk.h[3] = f2bf(f0.w);
  pk.h[4] = f2bf(f1.x); pk.h[5] = f2bf(f1.y);
  pk.h[6] = f2bf(f1.z); pk.h[7] = f2bf(f1.w);
  *(uint4*)(ps + (size_t)row * DD + c8 * 8) = pk.u;
}

// -------------------------------------------- B-fragment table precompute --
// B[(i,c_local), n] = k[i, c_local - n] if 0<=c_local-n<23 and i<23 else 0.
// K order: k = i*40 + c_local; chunk kk covers k in [32kk, 32kk+32).
// Lane layout matches MFMA B frag: n=lane&15, k8 = kk*4 + (lane>>4), j=0..7.
__global__ __launch_bounds__(64) void bfrag_kernel(
    const float* __restrict__ conv_k, uint16_t* __restrict__ btab)
{
  const int layer = blockIdx.x;
  const int lane = threadIdx.x;
  const int s = lane >> 4, n = lane & 15;
  for (int kk = 0; kk < 30; ++kk) {
    int k8 = kk * 4 + s;
    int i = k8 / 5;
    int c8 = k8 - i * 5;
    #pragma unroll
    for (int j = 0; j < 8; ++j) {
      int c = c8 * 8 + j;
      int jj = c - n;
      float v = (i < KS && jj >= 0 && jj < KS)
                    ? conv_k[layer * KS * KS + i * KS + jj] : 0.f;
      btab[(((size_t)layer * 30 + kk) * 64 + lane) * 8 + j] = f2bf(v);
    }
  }
}

// ----------------------------------------------------------- conv (MFMA) ---
// out[l,d] = sum_{i,j} in[l+i-11, d+j-11] k[i,j], as banded im2col GEMM.
// Block: one b, 64 l-rows, 4 waves = 4 d-groups of 16.
// LDS tile[t][c]: t=0..87 (l = l0-11+t), c=0..87 (input d = c-11), halo zero.
// Wave g: M=64 (4 mtiles), N=16 (d in [16g,16g+16)), K=960 (i*40+c_local),
// c_local = c - 16g. A frag: ds_read_b128; B frags preloaded in VGPRs.
#define TW 88
#define TR 88

__global__ __launch_bounds__(256, 2) void conv_mfma_kernel(
    const uint16_t* __restrict__ in, uint16_t* __restrict__ out,
    const uint16_t* __restrict__ btab, const float* __restrict__ conv_b,
    int layer)
{
  __shared__ uint16_t tile[TR * TW];
  const int tid = threadIdx.x;
  const int l0 = blockIdx.x * 64;
  const int b  = blockIdx.y;
  const int lane = tid & 63;
  const int g = tid >> 6;

  // preload B fragments (30 KB table, L2-hot) into 120 VGPRs
  v8bf bfr[30];
  const uint16_t* bt = btab + (size_t)layer * 30 * 512 + lane * 8;
  #pragma unroll
  for (int kk = 0; kk < 30; ++kk)
    bfr[kk] = *(const v8bf*)(bt + kk * 512);

  // zero tile, then stage valid rows (cols 11..74)
  for (int i = tid; i < TR * TW / 8; i += 256)
    ((uint4*)tile)[i] = make_uint4(0u, 0u, 0u, 0u);
  __syncthreads();
  const uint16_t* inb = in + (size_t)b * LL * DD;
  for (int idx = tid; idx < 86 * 8; idx += 256) {
    int t = idx >> 3, c8 = idx & 7;
    int gl = l0 - PAD + t;
    if (gl >= 0 && gl < LL) {
      uint4 v = *(const uint4*)(inb + (size_t)gl * DD + c8 * 8);
      uint16_t* dst = tile + t * TW + PAD + c8 * 8;
      dst[0] = (uint16_t)(v.x & 0xffffu); dst[1] = (uint16_t)(v.x >> 16);
      dst[2] = (uint16_t)(v.y & 0xffffu); dst[3] = (uint16_t)(v.y >> 16);
      dst[4] = (uint16_t)(v.z & 0xffffu); dst[5] = (uint16_t)(v.z >> 16);
      dst[6] = (uint16_t)(v.w & 0xffffu); dst[7] = (uint16_t)(v.w >> 16);
    }
  }
  __syncthreads();

  const int s = lane >> 4;
  const int m16 = lane & 15;
  v4f acc[4];
  #pragma unroll
  for (int m = 0; m < 4; ++m) acc[m] = (v4f){0.f, 0.f, 0.f, 0.f};

  #pragma unroll
  for (int kk = 0; kk < 30; ++kk) {
    int k8 = kk * 4 + s;
    int i = k8 / 5;            // kernel row (23 => zero-padded)
    int c8 = k8 - i * 5;       // which 8-wide c_local slice
    const uint16_t* ap = tile + (m16 + i) * TW + 16 * g + c8 * 8;
    v8bf a0 = *(const v8bf*)(ap);
    v8bf a1 = *(const v8bf*)(ap + 16 * TW);
    v8bf a2 = *(const v8bf*)(ap + 32 * TW);
    v8bf a3 = *(const v8bf*)(ap + 48 * TW);
    acc[0] = __builtin_amdgcn_mfma_f32_16x16x32_bf16(a0, bfr[kk], acc[0], 0, 0, 0);
    acc[1] = __builtin_amdgcn_mfma_f32_16x16x32_bf16(a1, bfr[kk], acc[1], 0, 0, 0);
    acc[2] = __builtin_amdgcn_mfma_f32_16x16x32_bf16(a2, bfr[kk], acc[2], 0, 0, 0);
    acc[3] = __builtin_amdgcn_mfma_f32_16x16x32_bf16(a3, bfr[kk], acc[3], 0, 0, 0);
  }

  const float bias = conv_b[layer];
  // D layout: col = lane&15 (d_local), row = s*4 + reg (within 16x16 tile)
  uint16_t* outb = out + ((size_t)b * LL + l0) * DD + 16 * g + m16;
  #pragma unroll
  for (int m = 0; m < 4; ++m) {
    #pragma unroll
    for (int r = 0; r < 4; ++r) {
      int row = m * 16 + s * 4 + r;
      outb[(size_t)row * DD] = f2bf(fmaxf(acc[m][r] + bias, 0.f));
    }
  }
}

// --------------------------------------------------- attention partials ----
#define PTS 68
#define HTS 69

__global__ __launch_bounds__(256) void attn_part_kernel(
    const uint16_t* __restrict__ ps, const float* __restrict__ amino_mask,
    const float* __restrict__ compound, const float* __restrict__ W_att,
    const float* __restrict__ b_att, float* __restrict__ pacc_part,
    float* __restrict__ msum_part)
{
  __shared__ float pt[64 * PTS];
  __shared__ float ht[64 * HTS];
  __shared__ float cvec[64];
  __shared__ float hvec[64];
  __shared__ float wvec[64];
  __shared__ float pacc_s[4][64];
  __shared__ float msum_s[64];

  const int chunk = blockIdx.x;
  const int b = blockIdx.y;
  const int tid = threadIdx.x;
  const int e = tid & 63;
  const int g = __builtin_amdgcn_readfirstlane(tid >> 6);

  float wreg[64];
  const float* wrow = W_att + (size_t)e * DD;
  #pragma unroll
  for (int d4 = 0; d4 < 16; ++d4) {
    float4 w = ((const float4*)wrow)[d4];
    wreg[4 * d4 + 0] = w.x; wreg[4 * d4 + 1] = w.y;
    wreg[4 * d4 + 2] = w.z; wreg[4 * d4 + 3] = w.w;
  }
  const float breg = b_att[e];
  if (tid < 64) cvec[tid] = compound[b * DD + tid];
  __syncthreads();

  if (tid < 64) {
    float a = breg;
    #pragma unroll
    for (int d4 = 0; d4 < 16; ++d4) {
      float4 c = ((const float4*)cvec)[d4];
      a = fmaf(c.x, wreg[4 * d4 + 0], a);
      a = fmaf(c.y, wreg[4 * d4 + 1], a);
      a = fmaf(c.z, wreg[4 * d4 + 2], a);
      a = fmaf(c.w, wreg[4 * d4 + 3], a);
    }
    hvec[tid] = fmaxf(a, 0.f);
  }

  float pacc = 0.f;
  float macc = 0.f;
  const uint16_t* psb = ps + (size_t)b * LL * DD;
  const float* pmb = amino_mask + (size_t)b * LL;

  const int t_beg = chunk * (LL / 4);
  for (int t0 = t_beg; t0 < t_beg + LL / 4; t0 += 64) {
    __syncthreads();
    for (int i = tid; i < 64 * 8; i += 256) {
      int r = i >> 3, c8 = i & 7;
      uint4 v = *(const uint4*)(psb + (size_t)(t0 + r) * DD + c8 * 8);
      float* dst = pt + r * PTS + c8 * 8;
      dst[0] = bf2f(v.x & 0xffffu); dst[1] = bf2f(v.x >> 16);
      dst[2] = bf2f(v.y & 0xffffu); dst[3] = bf2f(v.y >> 16);
      dst[4] = bf2f(v.z & 0xffffu); dst[5] = bf2f(v.z >> 16);
      dst[6] = bf2f(v.w & 0xffffu); dst[7] = bf2f(v.w >> 16);
    }
    if (tid < 64) macc += pmb[t0 + tid];
    __syncthreads();
    for (int rr = g * 16; rr < g * 16 + 16; ++rr) {
      float a = breg;
      #pragma unroll
      for (int d4 = 0; d4 < 16; ++d4) {
        float4 x = ((const float4*)(pt + rr * PTS))[d4];
        a = fmaf(x.x, wreg[4 * d4 + 0], a);
        a = fmaf(x.y, wreg[4 * d4 + 1], a);
        a = fmaf(x.z, wreg[4 * d4 + 2], a);
        a = fmaf(x.w, wreg[4 * d4 + 3], a);
      }
      float pm = pmb[t0 + rr];
      ht[rr * HTS + e] = fmaxf(a, 0.f) * pm;
    }
    __syncthreads();
    if (tid < 64) {
      float a = 0.f;
      #pragma unroll 8
      for (int dd = 0; dd < 64; ++dd) a = fmaf(ht[tid * HTS + dd], hvec[dd], a);
      wvec[tid] = tanhf(a);
    }
    __syncthreads();
    #pragma unroll
    for (int k = 0; k < 16; ++k) {
      int rr = g + 4 * k;
      pacc = fmaf(wvec[rr], ht[rr * HTS + e], pacc);
    }
  }
  pacc_s[g][e] = pacc;
  if (tid < 64) msum_s[tid] = macc;
  __syncthreads();
  if (tid < 64) {
    float p = pacc_s[0][tid] + pacc_s[1][tid] + pacc_s[2][tid] + pacc_s[3][tid];
    pacc_part[((size_t)b * 4 + chunk) * 64 + tid] = p;
  }
  if (tid == 0) {
    float den = 0.f;
    for (int i = 0; i < 64; ++i) den += msum_s[i];
    msum_part[b * 4 + chunk] = den;
  }
}

// --------------------------------------------------- finalize + FC head ----
__global__ __launch_bounds__(128) void attn_final_kernel(
    const float* __restrict__ compound, const float* __restrict__ pacc_part,
    const float* __restrict__ msum_part, const float* __restrict__ W_out,
    const float* __restrict__ b_out, const float* __restrict__ W_int,
    const float* __restrict__ b_int, float* __restrict__ outp)
{
  __shared__ float cat[128];
  __shared__ float cat2[128];
  const int b = blockIdx.x;
  const int tid = threadIdx.x;

  if (tid < 64) {
    float p = pacc_part[((size_t)b * 4 + 0) * 64 + tid]
            + pacc_part[((size_t)b * 4 + 1) * 64 + tid]
            + pacc_part[((size_t)b * 4 + 2) * 64 + tid]
            + pacc_part[((size_t)b * 4 + 3) * 64 + tid];
    float den = msum_part[b * 4 + 0] + msum_part[b * 4 + 1]
              + msum_part[b * 4 + 2] + msum_part[b * 4 + 3];
    cat[tid] = compound[b * DD + tid];
    cat[64 + tid] = p / (den + EPSF);
  }
  __syncthreads();
  {
    float a = b_out[tid];
    const float* wr = W_out + (size_t)tid * 128;
    #pragma unroll 8
    for (int dd = 0; dd < 128; ++dd) a = fmaf(wr[dd], cat[dd], a);
    cat2[tid] = fmaxf(a, 0.f);
  }
  __syncthreads();
  {
    float a = b_out[128 + tid];
    const float* wr = W_out + 128 * 128 + (size_t)tid * 128;
    #pragma unroll 8
    for (int dd = 0; dd < 128; ++dd) a = fmaf(wr[dd], cat2[dd], a);
    __syncthreads();
    cat[tid] = fmaxf(a, 0.f);
  }
  __syncthreads();
  if (tid < 2) {
    float a = b_int[tid];
    const float* wr = W_int + (size_t)tid * 128;
    #pragma unroll 8
    for (int dd = 0; dd < 128; ++dd) a = fmaf(wr[dd], cat[dd], a);
    outp[b * 2 + tid] = a;
  }
}

// -------------------------------------------------------------- launch -----
extern "C" void kernel_launch(void* const* d_in, const int* in_sizes, int n_in,
                              void* d_out, int out_size, void* d_ws, size_t ws_size,
                              hipStream_t stream) {
  const int*   atoms      = (const int*)d_in[0];
  const float* atoms_mask = (const float*)d_in[1];
  const float* adjacency  = (const float*)d_in[2];
  const int*   amino      = (const int*)d_in[3];
  const float* amino_mask = (const float*)d_in[4];
  const float* emb_fp     = (const float*)d_in[5];
  const float* emb_word   = (const float*)d_in[6];
  const float* W_gnn      = (const float*)d_in[7];
  const float* b_gnn      = (const float*)d_in[8];
  const float* conv_k     = (const float*)d_in[9];
  const float* conv_b     = (const float*)d_in[10];
  const float* W_att      = (const float*)d_in[11];
  const float* b_att      = (const float*)d_in[12];
  const float* W_out      = (const float*)d_in[13];
  const float* b_out      = (const float*)d_in[14];
  const float* W_int      = (const float*)d_in[15];
  const float* b_int      = (const float*)d_in[16];
  float* out = (float*)d_out;

  char* ws = (char*)d_ws;
  const size_t ps_bytes = (size_t)BB * LL * DD * 2;   // 64 MB each
  float*    compound  = (float*)ws;                                   // 64 KB
  uint16_t* ps_a      = (uint16_t*)(ws + 65536);
  uint16_t* ps_b      = (uint16_t*)(ws + 65536 + ps_bytes);
  uint16_t* btab      = (uint16_t*)(ws + 65536 + 2 * ps_bytes);       // 92160 B
  float*    pacc_part = (float*)(ws + 65536 + 2 * ps_bytes + 131072); // 256 KB
  float*    msum_part = (float*)(ws + 65536 + 2 * ps_bytes + 131072 + 262144);

  bfrag_kernel<<<3, 64, 0, stream>>>(conv_k, btab);
  gnn_kernel<<<BB, 256, 0, stream>>>(atoms, atoms_mask, adjacency, emb_fp,
                                     W_gnn, b_gnn, compound);
  gather_kernel<<<(BB * LL * DD / 8) / 256, 256, 0, stream>>>(amino, emb_word, ps_a);
  conv_mfma_kernel<<<dim3(LL / 64, BB), 256, 0, stream>>>(ps_a, ps_b, btab, conv_b, 0);
  conv_mfma_kernel<<<dim3(LL / 64, BB), 256, 0, stream>>>(ps_b, ps_a, btab, conv_b, 1);
  conv_mfma_kernel<<<dim3(LL / 64, BB), 256, 0, stream>>>(ps_a, ps_b, btab, conv_b, 2);
  attn_part_kernel<<<dim3(4, BB), 256, 0, stream>>>(ps_b, amino_mask, compound,
                                                    W_att, b_att, pacc_part, msum_part);
  attn_final_kernel<<<BB, 128, 0, stream>>>(compound, pacc_part, msum_part,
                                            W_out, b_out, W_int, b_int, out);
}

// Round 3
// 638.410 us; speedup vs baseline: 2.3477x; 1.1318x over previous
//
#include <hip/hip_runtime.h>
#include <hip/hip_bf16.h>
#include <cstdint>
#include <cstddef>

#define BB 256
#define NN 128
#define LL 2048
#define DD 64
#define KS 23
#define PAD 11
#define EPSF 1e-6f
#define ACH 16   // attention L-chunks

typedef __bf16 v8bf __attribute__((ext_vector_type(8)));
typedef float v4f __attribute__((ext_vector_type(4)));

__device__ __forceinline__ float bf2f(uint32_t u) {
  union { uint32_t i; float f; } c; c.i = u << 16; return c.f;
}
__device__ __forceinline__ uint16_t f2bf(float f) {
  union { float f; uint32_t i; } c; c.f = f;
  uint32_t i = c.i;
  return (uint16_t)((i + 0x7fffu + ((i >> 16) & 1u)) >> 16);
}

// ---------------------------------------------------------------- GNN ------
// One block per b, 1024 threads = 16 waves (4/SIMD for latency hiding).
__global__ __launch_bounds__(1024) void gnn_kernel(
    const int* __restrict__ atoms, const float* __restrict__ atoms_mask,
    const float* __restrict__ adj, const float* __restrict__ emb_fp,
    const float* __restrict__ W_gnn, const float* __restrict__ b_gnn,
    float* __restrict__ compound)
{
  __shared__ float xs[NN][DD];
  __shared__ float hs[NN][DD];
  const int b = blockIdx.x;
  const int tid = threadIdx.x;
  const int e = tid & 63;
  const int g = __builtin_amdgcn_readfirstlane(tid >> 6);  // 0..15

  for (int idx = tid; idx < NN * DD; idx += 1024) {
    int n = idx >> 6, d = idx & 63;
    int a = atoms[b * NN + n];
    xs[n][d] = emb_fp[(size_t)a * DD + d];
  }

  float wreg[DD];
  for (int layer = 0; layer < 3; ++layer) {
    const float* wrow = W_gnn + (size_t)layer * DD * DD + (size_t)e * DD;
    #pragma unroll
    for (int d4 = 0; d4 < DD / 4; ++d4) {
      float4 w = ((const float4*)wrow)[d4];
      wreg[4 * d4 + 0] = w.x; wreg[4 * d4 + 1] = w.y;
      wreg[4 * d4 + 2] = w.z; wreg[4 * d4 + 3] = w.w;
    }
    const float breg = b_gnn[layer * DD + e];
    __syncthreads();
    // hs = relu(xs @ W^T + b): wave g handles 8 rows
    for (int n = g * 8; n < g * 8 + 8; ++n) {
      float acc = breg;
      #pragma unroll
      for (int d4 = 0; d4 < DD / 4; ++d4) {
        float4 x = ((const float4*)&xs[n][0])[d4];
        acc = fmaf(x.x, wreg[4 * d4 + 0], acc);
        acc = fmaf(x.y, wreg[4 * d4 + 1], acc);
        acc = fmaf(x.z, wreg[4 * d4 + 2], acc);
        acc = fmaf(x.w, wreg[4 * d4 + 3], acc);
      }
      hs[n][e] = fmaxf(acc, 0.f);
    }
    __syncthreads();
    // xs += adj @ hs: wave g handles rows [8g, 8g+8) in two 4-row chunks
    const float* adjb = adj + (size_t)b * NN * NN;
    for (int nb = 0; nb < 2; ++nb) {
      int n0 = g * 8 + nb * 4;
      float a0 = 0.f, a1 = 0.f, a2 = 0.f, a3 = 0.f;
      const float* r0 = adjb + (size_t)(n0 + 0) * NN;
      const float* r1 = adjb + (size_t)(n0 + 1) * NN;
      const float* r2 = adjb + (size_t)(n0 + 2) * NN;
      const float* r3 = adjb + (size_t)(n0 + 3) * NN;
      #pragma unroll 8
      for (int m = 0; m < NN; ++m) {
        float h = hs[m][e];
        a0 = fmaf(r0[m], h, a0);
        a1 = fmaf(r1[m], h, a1);
        a2 = fmaf(r2[m], h, a2);
        a3 = fmaf(r3[m], h, a3);
      }
      xs[n0 + 0][e] += a0;
      xs[n0 + 1][e] += a1;
      xs[n0 + 2][e] += a2;
      xs[n0 + 3][e] += a3;
    }
    __syncthreads();
  }
  if (tid < 64) {
    float s = 0.f, den = 0.f;
    for (int n = 0; n < NN; ++n) {
      float m = atoms_mask[b * NN + n];
      s = fmaf(xs[n][tid], m, s);
      den += m;
    }
    compound[b * DD + tid] = s / (den + EPSF);
  }
}

// ------------------------------------------------------------- gather ------
__global__ __launch_bounds__(256) void gather_kernel(
    const int* __restrict__ amino, const float* __restrict__ emb_word,
    uint16_t* __restrict__ ps)
{
  int gid = blockIdx.x * 256 + threadIdx.x;
  int row = gid >> 3, c8 = gid & 7;
  int a = amino[row];
  const float* src = emb_word + (size_t)a * DD + c8 * 8;
  float4 f0 = ((const float4*)src)[0];
  float4 f1 = ((const float4*)src)[1];
  union { uint4 u; uint16_t h[8]; } pk;
  pk.h[0] = f2bf(f0.x); pk.h[1] = f2bf(f0.y);
  pk.h[2] = f2bf(f0.z); pk.h[3] = f2bf(f0.w);
  pk.h[4] = f2bf(f1.x); pk.h[5] = f2bf(f1.y);
  pk.h[6] = f2bf(f1.z); pk.h[7] = f2bf(f1.w);
  *(uint4*)(ps + (size_t)row * DD + c8 * 8) = pk.u;
}

// -------------------------------------------- B-fragment table precompute --
__global__ __launch_bounds__(64) void bfrag_kernel(
    const float* __restrict__ conv_k, uint16_t* __restrict__ btab)
{
  const int layer = blockIdx.x;
  const int lane = threadIdx.x;
  const int s = lane >> 4, n = lane & 15;
  for (int kk = 0; kk < 30; ++kk) {
    int k8 = kk * 4 + s;
    int i = k8 / 5;
    int c8 = k8 - i * 5;
    #pragma unroll
    for (int j = 0; j < 8; ++j) {
      int c = c8 * 8 + j;
      int jj = c - n;
      float v = (i < KS && jj >= 0 && jj < KS)
                    ? conv_k[layer * KS * KS + i * KS + jj] : 0.f;
      btab[(((size_t)layer * 30 + kk) * 64 + lane) * 8 + j] = f2bf(v);
    }
  }
}

// ----------------------------------------------------------- conv (MFMA) ---
#define TW 88
#define TR 88

__global__ __launch_bounds__(256, 2) void conv_mfma_kernel(
    const uint16_t* __restrict__ in, uint16_t* __restrict__ out,
    const uint16_t* __restrict__ btab, const float* __restrict__ conv_b,
    int layer)
{
  __shared__ uint16_t tile[TR * TW];
  const int tid = threadIdx.x;
  const int l0 = blockIdx.x * 64;
  const int b  = blockIdx.y;
  const int lane = tid & 63;
  const int g = tid >> 6;

  v8bf bfr[30];
  const uint16_t* bt = btab + (size_t)layer * 30 * 512 + lane * 8;
  #pragma unroll
  for (int kk = 0; kk < 30; ++kk)
    bfr[kk] = *(const v8bf*)(bt + kk * 512);

  for (int i = tid; i < TR * TW / 8; i += 256)
    ((uint4*)tile)[i] = make_uint4(0u, 0u, 0u, 0u);
  __syncthreads();
  const uint16_t* inb = in + (size_t)b * LL * DD;
  for (int idx = tid; idx < 86 * 8; idx += 256) {
    int t = idx >> 3, c8 = idx & 7;
    int gl = l0 - PAD + t;
    if (gl >= 0 && gl < LL) {
      uint4 v = *(const uint4*)(inb + (size_t)gl * DD + c8 * 8);
      uint16_t* dst = tile + t * TW + PAD + c8 * 8;
      dst[0] = (uint16_t)(v.x & 0xffffu); dst[1] = (uint16_t)(v.x >> 16);
      dst[2] = (uint16_t)(v.y & 0xffffu); dst[3] = (uint16_t)(v.y >> 16);
      dst[4] = (uint16_t)(v.z & 0xffffu); dst[5] = (uint16_t)(v.z >> 16);
      dst[6] = (uint16_t)(v.w & 0xffffu); dst[7] = (uint16_t)(v.w >> 16);
    }
  }
  __syncthreads();

  const int s = lane >> 4;
  const int m16 = lane & 15;
  v4f acc[4];
  #pragma unroll
  for (int m = 0; m < 4; ++m) acc[m] = (v4f){0.f, 0.f, 0.f, 0.f};

  #pragma unroll
  for (int kk = 0; kk < 30; ++kk) {
    int k8 = kk * 4 + s;
    int i = k8 / 5;
    int c8 = k8 - i * 5;
    const uint16_t* ap = tile + (m16 + i) * TW + 16 * g + c8 * 8;
    v8bf a0 = *(const v8bf*)(ap);
    v8bf a1 = *(const v8bf*)(ap + 16 * TW);
    v8bf a2 = *(const v8bf*)(ap + 32 * TW);
    v8bf a3 = *(const v8bf*)(ap + 48 * TW);
    acc[0] = __builtin_amdgcn_mfma_f32_16x16x32_bf16(a0, bfr[kk], acc[0], 0, 0, 0);
    acc[1] = __builtin_amdgcn_mfma_f32_16x16x32_bf16(a1, bfr[kk], acc[1], 0, 0, 0);
    acc[2] = __builtin_amdgcn_mfma_f32_16x16x32_bf16(a2, bfr[kk], acc[2], 0, 0, 0);
    acc[3] = __builtin_amdgcn_mfma_f32_16x16x32_bf16(a3, bfr[kk], acc[3], 0, 0, 0);
  }

  const float bias = conv_b[layer];
  uint16_t* outb = out + ((size_t)b * LL + l0) * DD + 16 * g + m16;
  #pragma unroll
  for (int m = 0; m < 4; ++m) {
    #pragma unroll
    for (int r = 0; r < 4; ++r) {
      int row = m * 16 + s * 4 + r;
      outb[(size_t)row * DD] = f2bf(fmaxf(acc[m][r] + bias, 0.f));
    }
  }
}

// --------------------------------------------------- attention partials ----
#define PTS 68
#define HTS 69

__global__ __launch_bounds__(256) void attn_part_kernel(
    const uint16_t* __restrict__ ps, const float* __restrict__ amino_mask,
    const float* __restrict__ compound, const float* __restrict__ W_att,
    const float* __restrict__ b_att, float* __restrict__ pacc_part,
    float* __restrict__ msum_part)
{
  __shared__ float pt[64 * PTS];
  __shared__ float ht[64 * HTS];
  __shared__ float cvec[64];
  __shared__ float hvec[64];
  __shared__ float wvec[64];
  __shared__ float pacc_s[4][64];
  __shared__ float msum_s[64];

  const int chunk = blockIdx.x;
  const int b = blockIdx.y;
  const int tid = threadIdx.x;
  const int e = tid & 63;
  const int g = __builtin_amdgcn_readfirstlane(tid >> 6);

  float wreg[64];
  const float* wrow = W_att + (size_t)e * DD;
  #pragma unroll
  for (int d4 = 0; d4 < 16; ++d4) {
    float4 w = ((const float4*)wrow)[d4];
    wreg[4 * d4 + 0] = w.x; wreg[4 * d4 + 1] = w.y;
    wreg[4 * d4 + 2] = w.z; wreg[4 * d4 + 3] = w.w;
  }
  const float breg = b_att[e];
  if (tid < 64) cvec[tid] = compound[b * DD + tid];
  __syncthreads();

  if (tid < 64) {
    float a = breg;
    #pragma unroll
    for (int d4 = 0; d4 < 16; ++d4) {
      float4 c = ((const float4*)cvec)[d4];
      a = fmaf(c.x, wreg[4 * d4 + 0], a);
      a = fmaf(c.y, wreg[4 * d4 + 1], a);
      a = fmaf(c.z, wreg[4 * d4 + 2], a);
      a = fmaf(c.w, wreg[4 * d4 + 3], a);
    }
    hvec[tid] = fmaxf(a, 0.f);
  }

  float pacc = 0.f;
  float macc = 0.f;
  const uint16_t* psb = ps + (size_t)b * LL * DD;
  const float* pmb = amino_mask + (size_t)b * LL;

  const int t_beg = chunk * (LL / ACH);
  for (int t0 = t_beg; t0 < t_beg + LL / ACH; t0 += 64) {
    __syncthreads();
    for (int i = tid; i < 64 * 8; i += 256) {
      int r = i >> 3, c8 = i & 7;
      uint4 v = *(const uint4*)(psb + (size_t)(t0 + r) * DD + c8 * 8);
      float* dst = pt + r * PTS + c8 * 8;
      dst[0] = bf2f(v.x & 0xffffu); dst[1] = bf2f(v.x >> 16);
      dst[2] = bf2f(v.y & 0xffffu); dst[3] = bf2f(v.y >> 16);
      dst[4] = bf2f(v.z & 0xffffu); dst[5] = bf2f(v.z >> 16);
      dst[6] = bf2f(v.w & 0xffffu); dst[7] = bf2f(v.w >> 16);
    }
    if (tid < 64) macc += pmb[t0 + tid];
    __syncthreads();
    for (int rr = g * 16; rr < g * 16 + 16; ++rr) {
      float a = breg;
      #pragma unroll
      for (int d4 = 0; d4 < 16; ++d4) {
        float4 x = ((const float4*)(pt + rr * PTS))[d4];
        a = fmaf(x.x, wreg[4 * d4 + 0], a);
        a = fmaf(x.y, wreg[4 * d4 + 1], a);
        a = fmaf(x.z, wreg[4 * d4 + 2], a);
        a = fmaf(x.w, wreg[4 * d4 + 3], a);
      }
      float pm = pmb[t0 + rr];
      ht[rr * HTS + e] = fmaxf(a, 0.f) * pm;
    }
    __syncthreads();
    if (tid < 64) {
      float a = 0.f;
      #pragma unroll 8
      for (int dd = 0; dd < 64; ++dd) a = fmaf(ht[tid * HTS + dd], hvec[dd], a);
      wvec[tid] = tanhf(a);
    }
    __syncthreads();
    #pragma unroll
    for (int k = 0; k < 16; ++k) {
      int rr = g + 4 * k;
      pacc = fmaf(wvec[rr], ht[rr * HTS + e], pacc);
    }
  }
  pacc_s[g][e] = pacc;
  if (tid < 64) msum_s[tid] = macc;
  __syncthreads();
  if (tid < 64) {
    float p = pacc_s[0][tid] + pacc_s[1][tid] + pacc_s[2][tid] + pacc_s[3][tid];
    pacc_part[((size_t)b * ACH + chunk) * 64 + tid] = p;
  }
  if (tid == 0) {
    float den = 0.f;
    for (int i = 0; i < 64; ++i) den += msum_s[i];
    msum_part[b * ACH + chunk] = den;
  }
}

// --------------------------------------------------- finalize + FC head ----
__global__ __launch_bounds__(128) void attn_final_kernel(
    const float* __restrict__ compound, const float* __restrict__ pacc_part,
    const float* __restrict__ msum_part, const float* __restrict__ W_out,
    const float* __restrict__ b_out, const float* __restrict__ W_int,
    const float* __restrict__ b_int, float* __restrict__ outp)
{
  __shared__ float cat[128];
  __shared__ float cat2[128];
  const int b = blockIdx.x;
  const int tid = threadIdx.x;

  if (tid < 64) {
    float p = 0.f, den = 0.f;
    #pragma unroll
    for (int c = 0; c < ACH; ++c) {
      p += pacc_part[((size_t)b * ACH + c) * 64 + tid];
      den += msum_part[b * ACH + c];
    }
    cat[tid] = compound[b * DD + tid];
    cat[64 + tid] = p / (den + EPSF);
  }
  __syncthreads();
  {
    float a = b_out[tid];
    const float* wr = W_out + (size_t)tid * 128;
    #pragma unroll 8
    for (int dd = 0; dd < 128; ++dd) a = fmaf(wr[dd], cat[dd], a);
    cat2[tid] = fmaxf(a, 0.f);
  }
  __syncthreads();
  {
    float a = b_out[128 + tid];
    const float* wr = W_out + 128 * 128 + (size_t)tid * 128;
    #pragma unroll 8
    for (int dd = 0; dd < 128; ++dd) a = fmaf(wr[dd], cat2[dd], a);
    __syncthreads();
    cat[tid] = fmaxf(a, 0.f);
  }
  __syncthreads();
  if (tid < 2) {
    float a = b_int[tid];
    const float* wr = W_int + (size_t)tid * 128;
    #pragma unroll 8
    for (int dd = 0; dd < 128; ++dd) a = fmaf(wr[dd], cat[dd], a);
    outp[b * 2 + tid] = a;
  }
}

// -------------------------------------------------------------- launch -----
extern "C" void kernel_launch(void* const* d_in, const int* in_sizes, int n_in,
                              void* d_out, int out_size, void* d_ws, size_t ws_size,
                              hipStream_t stream) {
  const int*   atoms      = (const int*)d_in[0];
  const float* atoms_mask = (const float*)d_in[1];
  const float* adjacency  = (const float*)d_in[2];
  const int*   amino      = (const int*)d_in[3];
  const float* amino_mask = (const float*)d_in[4];
  const float* emb_fp     = (const float*)d_in[5];
  const float* emb_word   = (const float*)d_in[6];
  const float* W_gnn      = (const float*)d_in[7];
  const float* b_gnn      = (const float*)d_in[8];
  const float* conv_k     = (const float*)d_in[9];
  const float* conv_b     = (const float*)d_in[10];
  const float* W_att      = (const float*)d_in[11];
  const float* b_att      = (const float*)d_in[12];
  const float* W_out      = (const float*)d_in[13];
  const float* b_out      = (const float*)d_in[14];
  const float* W_int      = (const float*)d_in[15];
  const float* b_int      = (const float*)d_in[16];
  float* out = (float*)d_out;

  char* ws = (char*)d_ws;
  const size_t ps_bytes = (size_t)BB * LL * DD * 2;   // 64 MB each
  float*    compound  = (float*)ws;                                   // 64 KB
  uint16_t* ps_a      = (uint16_t*)(ws + 65536);
  uint16_t* ps_b      = (uint16_t*)(ws + 65536 + ps_bytes);
  uint16_t* btab      = (uint16_t*)(ws + 65536 + 2 * ps_bytes);       // 92160 B
  // pacc/msum alias the ps_a region: ps_a is dead once conv layer 2 has run,
  // and attn_part (the only writer of these) is ordered after conv2.
  float*    pacc_part = (float*)ps_a;                                 // 1 MB
  float*    msum_part = (float*)(ws + 65536 + (size_t)BB * ACH * 64 * 4);

  bfrag_kernel<<<3, 64, 0, stream>>>(conv_k, btab);
  gnn_kernel<<<BB, 1024, 0, stream>>>(atoms, atoms_mask, adjacency, emb_fp,
                                      W_gnn, b_gnn, compound);
  gather_kernel<<<(BB * LL * DD / 8) / 256, 256, 0, stream>>>(amino, emb_word, ps_a);
  conv_mfma_kernel<<<dim3(LL / 64, BB), 256, 0, stream>>>(ps_a, ps_b, btab, conv_b, 0);
  conv_mfma_kernel<<<dim3(LL / 64, BB), 256, 0, stream>>>(ps_b, ps_a, btab, conv_b, 1);
  conv_mfma_kernel<<<dim3(LL / 64, BB), 256, 0, stream>>>(ps_a, ps_b, btab, conv_b, 2);
  attn_part_kernel<<<dim3(ACH, BB), 256, 0, stream>>>(ps_b, amino_mask, compound,
                                                      W_att, b_att, pacc_part, msum_part);
  attn_final_kernel<<<BB, 128, 0, stream>>>(compound, pacc_part, msum_part,
                                            W_out, b_out, W_int, b_int, out);
}

// Round 4
// 544.997 us; speedup vs baseline: 2.7501x; 1.1714x over previous
//
#include <hip/hip_runtime.h>
#include <hip/hip_bf16.h>
#include <cstdint>
#include <cstddef>

#define BB 256
#define NN 128
#define LL 2048
#define DD 64
#define KS 23
#define PAD 11
#define EPSF 1e-6f
#define ACH 8    // attention L-chunks: block covers 256 rows

typedef __bf16 v8bf __attribute__((ext_vector_type(8)));
typedef float v4f __attribute__((ext_vector_type(4)));

__device__ __forceinline__ float bf2f(uint32_t u) {
  union { uint32_t i; float f; } c; c.i = u << 16; return c.f;
}
__device__ __forceinline__ uint16_t f2bf(float f) {
  union { float f; uint32_t i; } c; c.f = f;
  uint32_t i = c.i;
  return (uint16_t)((i + 0x7fffu + ((i >> 16) & 1u)) >> 16);
}
__device__ __forceinline__ __bf16 f2bf16(float f) {
  union { uint16_t u; __bf16 h; } c; c.u = f2bf(f); return c.h;
}

// ---------------------------------------------------------------- GNN ------
// One block per b, 1024 threads = 16 waves. Epilogue also computes
// hvec = relu(W_att @ compound + b_att) for the attention kernel.
__global__ __launch_bounds__(1024) void gnn_kernel(
    const int* __restrict__ atoms, const float* __restrict__ atoms_mask,
    const float* __restrict__ adj, const float* __restrict__ emb_fp,
    const float* __restrict__ W_gnn, const float* __restrict__ b_gnn,
    const float* __restrict__ W_att, const float* __restrict__ b_att,
    float* __restrict__ compound, float* __restrict__ hvec_g)
{
  __shared__ float xs[NN][DD];
  __shared__ float hs[NN][DD];
  const int b = blockIdx.x;
  const int tid = threadIdx.x;
  const int e = tid & 63;
  const int g = __builtin_amdgcn_readfirstlane(tid >> 6);  // 0..15

  for (int idx = tid; idx < NN * DD; idx += 1024) {
    int n = idx >> 6, d = idx & 63;
    int a = atoms[b * NN + n];
    xs[n][d] = emb_fp[(size_t)a * DD + d];
  }

  float wreg[DD];
  for (int layer = 0; layer < 3; ++layer) {
    const float* wrow = W_gnn + (size_t)layer * DD * DD + (size_t)e * DD;
    #pragma unroll
    for (int d4 = 0; d4 < DD / 4; ++d4) {
      float4 w = ((const float4*)wrow)[d4];
      wreg[4 * d4 + 0] = w.x; wreg[4 * d4 + 1] = w.y;
      wreg[4 * d4 + 2] = w.z; wreg[4 * d4 + 3] = w.w;
    }
    const float breg = b_gnn[layer * DD + e];
    __syncthreads();
    for (int n = g * 8; n < g * 8 + 8; ++n) {
      float acc = breg;
      #pragma unroll
      for (int d4 = 0; d4 < DD / 4; ++d4) {
        float4 x = ((const float4*)&xs[n][0])[d4];
        acc = fmaf(x.x, wreg[4 * d4 + 0], acc);
        acc = fmaf(x.y, wreg[4 * d4 + 1], acc);
        acc = fmaf(x.z, wreg[4 * d4 + 2], acc);
        acc = fmaf(x.w, wreg[4 * d4 + 3], acc);
      }
      hs[n][e] = fmaxf(acc, 0.f);
    }
    __syncthreads();
    const float* adjb = adj + (size_t)b * NN * NN;
    for (int nb = 0; nb < 2; ++nb) {
      int n0 = g * 8 + nb * 4;
      float a0 = 0.f, a1 = 0.f, a2 = 0.f, a3 = 0.f;
      const float* r0 = adjb + (size_t)(n0 + 0) * NN;
      const float* r1 = adjb + (size_t)(n0 + 1) * NN;
      const float* r2 = adjb + (size_t)(n0 + 2) * NN;
      const float* r3 = adjb + (size_t)(n0 + 3) * NN;
      #pragma unroll 8
      for (int m = 0; m < NN; ++m) {
        float h = hs[m][e];
        a0 = fmaf(r0[m], h, a0);
        a1 = fmaf(r1[m], h, a1);
        a2 = fmaf(r2[m], h, a2);
        a3 = fmaf(r3[m], h, a3);
      }
      xs[n0 + 0][e] += a0;
      xs[n0 + 1][e] += a1;
      xs[n0 + 2][e] += a2;
      xs[n0 + 3][e] += a3;
    }
    __syncthreads();
  }
  // compound + hvec epilogue
  if (tid < 64) {
    float s = 0.f, den = 0.f;
    for (int n = 0; n < NN; ++n) {
      float m = atoms_mask[b * NN + n];
      s = fmaf(xs[n][tid], m, s);
      den += m;
    }
    float c = s / (den + EPSF);
    compound[b * DD + tid] = c;
    hs[0][tid] = c;            // reuse hs row 0 as cvec
  }
  __syncthreads();
  if (tid < 64) {
    float a = b_att[tid];
    const float* wr = W_att + (size_t)tid * DD;
    #pragma unroll
    for (int d4 = 0; d4 < 16; ++d4) {
      float4 w = ((const float4*)wr)[d4];
      float4 c = ((const float4*)&hs[0][0])[d4];
      a = fmaf(w.x, c.x, a); a = fmaf(w.y, c.y, a);
      a = fmaf(w.z, c.z, a); a = fmaf(w.w, c.w, a);
    }
    hvec_g[b * DD + tid] = fmaxf(a, 0.f);
  }
}

// ------------------------------------------------------------- gather ------
__global__ __launch_bounds__(256) void gather_kernel(
    const int* __restrict__ amino, const float* __restrict__ emb_word,
    uint16_t* __restrict__ ps)
{
  int gid = blockIdx.x * 256 + threadIdx.x;
  int row = gid >> 3, c8 = gid & 7;
  int a = amino[row];
  const float* src = emb_word + (size_t)a * DD + c8 * 8;
  float4 f0 = ((const float4*)src)[0];
  float4 f1 = ((const float4*)src)[1];
  union { uint4 u; uint16_t h[8]; } pk;
  pk.h[0] = f2bf(f0.x); pk.h[1] = f2bf(f0.y);
  pk.h[2] = f2bf(f0.z); pk.h[3] = f2bf(f0.w);
  pk.h[4] = f2bf(f1.x); pk.h[5] = f2bf(f1.y);
  pk.h[6] = f2bf(f1.z); pk.h[7] = f2bf(f1.w);
  *(uint4*)(ps + (size_t)row * DD + c8 * 8) = pk.u;
}

// -------------------------------------------- B-fragment table precompute --
__global__ __launch_bounds__(64) void bfrag_kernel(
    const float* __restrict__ conv_k, uint16_t* __restrict__ btab)
{
  const int layer = blockIdx.x;
  const int lane = threadIdx.x;
  const int s = lane >> 4, n = lane & 15;
  for (int kk = 0; kk < 30; ++kk) {
    int k8 = kk * 4 + s;
    int i = k8 / 5;
    int c8 = k8 - i * 5;
    #pragma unroll
    for (int j = 0; j < 8; ++j) {
      int c = c8 * 8 + j;
      int jj = c - n;
      float v = (i < KS && jj >= 0 && jj < KS)
                    ? conv_k[layer * KS * KS + i * KS + jj] : 0.f;
      btab[(((size_t)layer * 30 + kk) * 64 + lane) * 8 + j] = f2bf(v);
    }
  }
}

// ----------------------------------------------------------- conv (MFMA) ---
#define TW 88
#define TR 88

__global__ __launch_bounds__(256, 2) void conv_mfma_kernel(
    const uint16_t* __restrict__ in, uint16_t* __restrict__ out,
    const uint16_t* __restrict__ btab, const float* __restrict__ conv_b,
    int layer)
{
  __shared__ uint16_t tile[TR * TW];
  const int tid = threadIdx.x;
  const int l0 = blockIdx.x * 64;
  const int b  = blockIdx.y;
  const int lane = tid & 63;
  const int g = tid >> 6;

  v8bf bfr[30];
  const uint16_t* bt = btab + (size_t)layer * 30 * 512 + lane * 8;
  #pragma unroll
  for (int kk = 0; kk < 30; ++kk)
    bfr[kk] = *(const v8bf*)(bt + kk * 512);

  for (int i = tid; i < TR * TW / 8; i += 256)
    ((uint4*)tile)[i] = make_uint4(0u, 0u, 0u, 0u);
  __syncthreads();
  const uint16_t* inb = in + (size_t)b * LL * DD;
  for (int idx = tid; idx < 86 * 8; idx += 256) {
    int t = idx >> 3, c8 = idx & 7;
    int gl = l0 - PAD + t;
    if (gl >= 0 && gl < LL) {
      uint4 v = *(const uint4*)(inb + (size_t)gl * DD + c8 * 8);
      uint16_t* dst = tile + t * TW + PAD + c8 * 8;
      dst[0] = (uint16_t)(v.x & 0xffffu); dst[1] = (uint16_t)(v.x >> 16);
      dst[2] = (uint16_t)(v.y & 0xffffu); dst[3] = (uint16_t)(v.y >> 16);
      dst[4] = (uint16_t)(v.z & 0xffffu); dst[5] = (uint16_t)(v.z >> 16);
      dst[6] = (uint16_t)(v.w & 0xffffu); dst[7] = (uint16_t)(v.w >> 16);
    }
  }
  __syncthreads();

  const int s = lane >> 4;
  const int m16 = lane & 15;
  v4f acc[4];
  #pragma unroll
  for (int m = 0; m < 4; ++m) acc[m] = (v4f){0.f, 0.f, 0.f, 0.f};

  #pragma unroll
  for (int kk = 0; kk < 30; ++kk) {
    int k8 = kk * 4 + s;
    int i = k8 / 5;
    int c8 = k8 - i * 5;
    const uint16_t* ap = tile + (m16 + i) * TW + 16 * g + c8 * 8;
    v8bf a0 = *(const v8bf*)(ap);
    v8bf a1 = *(const v8bf*)(ap + 16 * TW);
    v8bf a2 = *(const v8bf*)(ap + 32 * TW);
    v8bf a3 = *(const v8bf*)(ap + 48 * TW);
    acc[0] = __builtin_amdgcn_mfma_f32_16x16x32_bf16(a0, bfr[kk], acc[0], 0, 0, 0);
    acc[1] = __builtin_amdgcn_mfma_f32_16x16x32_bf16(a1, bfr[kk], acc[1], 0, 0, 0);
    acc[2] = __builtin_amdgcn_mfma_f32_16x16x32_bf16(a2, bfr[kk], acc[2], 0, 0, 0);
    acc[3] = __builtin_amdgcn_mfma_f32_16x16x32_bf16(a3, bfr[kk], acc[3], 0, 0, 0);
  }

  const float bias = conv_b[layer];
  uint16_t* outb = out + ((size_t)b * LL + l0) * DD + 16 * g + m16;
  #pragma unroll
  for (int m = 0; m < 4; ++m) {
    #pragma unroll
    for (int r = 0; r < 4; ++r) {
      int row = m * 16 + s * 4 + r;
      outb[(size_t)row * DD] = f2bf(fmaxf(acc[m][r] + bias, 0.f));
    }
  }
}

// --------------------------------------------- attention partials (MFMA) ---
// hs = relu(ps @ W_att^T + b_att) * mask via mfma 16x16x32 bf16.
// Block: 256 rows of one b (wave w owns rows [chunk*256+w*64, +64), two
// 32-row steps). A-frags straight from global bf16 ps; B = W_att (bf16,
// built per block). ht round-trip in per-wave LDS for the tanh row-dot;
// protein accumulation stays in registers (cross-s shuffle at the end).
#define HTS2 66

__global__ __launch_bounds__(256) void attn_part_kernel(
    const uint16_t* __restrict__ ps, const float* __restrict__ amino_mask,
    const float* __restrict__ hvec_g, const float* __restrict__ W_att,
    const float* __restrict__ b_att, float* __restrict__ pacc_part,
    float* __restrict__ msum_part)
{
  __shared__ float ht[4][32 * HTS2];
  __shared__ float pm_s[4][64];
  __shared__ float wv_s[4][32];
  __shared__ float hv_s[64];

  const int chunk = blockIdx.x;
  const int b = blockIdx.y;
  const int tid = threadIdx.x;
  const int lane = tid & 63;
  const int w = tid >> 6;
  const int m16 = lane & 15;
  const int s = lane >> 4;

  // B fragments: B[k=d][n=e] = W_att[e][d], e = nt*16+m16, d = kc*32+s*8+j
  v8bf bfrB[2][4];
  float bias[4];
  #pragma unroll
  for (int nt = 0; nt < 4; ++nt) {
    bias[nt] = b_att[nt * 16 + m16];
    const float* wr = W_att + (size_t)(nt * 16 + m16) * DD + s * 8;
    #pragma unroll
    for (int kc = 0; kc < 2; ++kc) {
      float4 f0 = ((const float4*)(wr + kc * 32))[0];
      float4 f1 = ((const float4*)(wr + kc * 32))[1];
      v8bf bb;
      bb[0] = f2bf16(f0.x); bb[1] = f2bf16(f0.y);
      bb[2] = f2bf16(f0.z); bb[3] = f2bf16(f0.w);
      bb[4] = f2bf16(f1.x); bb[5] = f2bf16(f1.y);
      bb[6] = f2bf16(f1.z); bb[7] = f2bf16(f1.w);
      bfrB[kc][nt] = bb;
    }
  }
  if (tid < 64) hv_s[tid] = hvec_g[b * DD + tid];

  const int rowbase = chunk * 256 + w * 64;
  const float* pmb = amino_mask + (size_t)b * LL;
  pm_s[w][lane] = pmb[rowbase + lane];
  const float macc = pm_s[w][lane];   // this lane's mask value (for msum)
  __syncthreads();

  float pacc[4] = {0.f, 0.f, 0.f, 0.f};
  const uint16_t* psb = ps + ((size_t)b * LL + rowbase) * DD;

  #pragma unroll
  for (int step = 0; step < 2; ++step) {
    const uint16_t* pr = psb + (size_t)step * 32 * DD;
    // A-frags: 2 m-tiles x 2 k-chunks, straight from global (16B aligned)
    v8bf A[2][2];
    #pragma unroll
    for (int mt = 0; mt < 2; ++mt)
      #pragma unroll
      for (int kc = 0; kc < 2; ++kc)
        A[mt][kc] = *(const v8bf*)(pr + (mt * 16 + m16) * DD + kc * 32 + s * 8);

    v4f acc[2][4];
    #pragma unroll
    for (int mt = 0; mt < 2; ++mt)
      #pragma unroll
      for (int nt = 0; nt < 4; ++nt)
        acc[mt][nt] = (v4f){0.f, 0.f, 0.f, 0.f};
    #pragma unroll
    for (int kc = 0; kc < 2; ++kc)
      #pragma unroll
      for (int mt = 0; mt < 2; ++mt)
        #pragma unroll
        for (int nt = 0; nt < 4; ++nt)
          acc[mt][nt] = __builtin_amdgcn_mfma_f32_16x16x32_bf16(
              A[mt][kc], bfrB[kc][nt], acc[mt][nt], 0, 0, 0);

    // relu + bias + mask; keep vals in regs, mirror into per-wave LDS
    float vals[2][4][4];
    float* htw = ht[w];
    #pragma unroll
    for (int mt = 0; mt < 2; ++mt)
      #pragma unroll
      for (int r = 0; r < 4; ++r) {
        int row = mt * 16 + s * 4 + r;          // 0..31
        float pm = pm_s[w][step * 32 + row];
        #pragma unroll
        for (int nt = 0; nt < 4; ++nt) {
          float v = fmaxf(acc[mt][nt][r] + bias[nt], 0.f) * pm;
          vals[mt][nt][r] = v;
          htw[row * HTS2 + nt * 16 + m16] = v;
        }
      }
    __syncthreads();

    // weights: w[row] = tanh(sum_e ht[row][e] * hv[e]); two lanes per row
    {
      int row = lane & 31, eh = lane >> 5;
      const float* hr = ht[w] + row * HTS2 + eh * 32;
      const float* hv = hv_s + eh * 32;
      float d = 0.f;
      #pragma unroll
      for (int t = 0; t < 8; ++t) {
        float4 hh = *(const float4*)(hr + 4 * t);
        float4 vv = *(const float4*)(hv + 4 * t);
        d = fmaf(hh.x, vv.x, d); d = fmaf(hh.y, vv.y, d);
        d = fmaf(hh.z, vv.z, d); d = fmaf(hh.w, vv.w, d);
      }
      d += __shfl_xor(d, 32);
      float wt = tanhf(d);
      if (lane < 32) wv_s[w][row] = wt;
    }
    __syncthreads();

    // pacc[nt] += w[row] * vals  (col = nt*16+m16 fixed per lane)
    #pragma unroll
    for (int mt = 0; mt < 2; ++mt)
      #pragma unroll
      for (int r = 0; r < 4; ++r) {
        float wt = wv_s[w][mt * 16 + s * 4 + r];
        #pragma unroll
        for (int nt = 0; nt < 4; ++nt)
          pacc[nt] = fmaf(wt, vals[mt][nt][r], pacc[nt]);
      }
    __syncthreads();
  }

  // reduce pacc across the 4 s-groups; lane<16 writes cols nt*16+m16
  const size_t idx = ((size_t)b * ACH + chunk) * 4 + w;
  #pragma unroll
  for (int nt = 0; nt < 4; ++nt) {
    float p = pacc[nt];
    p += __shfl_xor(p, 16);
    p += __shfl_xor(p, 32);
    if (m16 == lane)   // lanes 0..15
      pacc_part[idx * 64 + nt * 16 + lane] = p;
  }
  // mask sum for this wave's 64 rows
  float m = macc;
  #pragma unroll
  for (int off = 1; off < 64; off <<= 1) m += __shfl_xor(m, off);
  if (lane == 0) msum_part[idx] = m;
}

// --------------------------------------------------- finalize + FC head ----
__global__ __launch_bounds__(128) void attn_final_kernel(
    const float* __restrict__ compound, const float* __restrict__ pacc_part,
    const float* __restrict__ msum_part, const float* __restrict__ W_out,
    const float* __restrict__ b_out, const float* __restrict__ W_int,
    const float* __restrict__ b_int, float* __restrict__ outp)
{
  __shared__ float cat[128];
  __shared__ float cat2[128];
  const int b = blockIdx.x;
  const int tid = threadIdx.x;

  if (tid < 64) {
    float p = 0.f, den = 0.f;
    #pragma unroll 4
    for (int c = 0; c < ACH * 4; ++c) {
      p += pacc_part[((size_t)b * ACH * 4 + c) * 64 + tid];
      den += msum_part[b * ACH * 4 + c];
    }
    cat[tid] = compound[b * DD + tid];
    cat[64 + tid] = p / (den + EPSF);
  }
  __syncthreads();
  {
    float a = b_out[tid];
    const float* wr = W_out + (size_t)tid * 128;
    #pragma unroll 8
    for (int dd = 0; dd < 128; ++dd) a = fmaf(wr[dd], cat[dd], a);
    cat2[tid] = fmaxf(a, 0.f);
  }
  __syncthreads();
  {
    float a = b_out[128 + tid];
    const float* wr = W_out + 128 * 128 + (size_t)tid * 128;
    #pragma unroll 8
    for (int dd = 0; dd < 128; ++dd) a = fmaf(wr[dd], cat2[dd], a);
    __syncthreads();
    cat[tid] = fmaxf(a, 0.f);
  }
  __syncthreads();
  if (tid < 2) {
    float a = b_int[tid];
    const float* wr = W_int + (size_t)tid * 128;
    #pragma unroll 8
    for (int dd = 0; dd < 128; ++dd) a = fmaf(wr[dd], cat[dd], a);
    outp[b * 2 + tid] = a;
  }
}

// -------------------------------------------------------------- launch -----
extern "C" void kernel_launch(void* const* d_in, const int* in_sizes, int n_in,
                              void* d_out, int out_size, void* d_ws, size_t ws_size,
                              hipStream_t stream) {
  const int*   atoms      = (const int*)d_in[0];
  const float* atoms_mask = (const float*)d_in[1];
  const float* adjacency  = (const float*)d_in[2];
  const int*   amino      = (const int*)d_in[3];
  const float* amino_mask = (const float*)d_in[4];
  const float* emb_fp     = (const float*)d_in[5];
  const float* emb_word   = (const float*)d_in[6];
  const float* W_gnn      = (const float*)d_in[7];
  const float* b_gnn      = (const float*)d_in[8];
  const float* conv_k     = (const float*)d_in[9];
  const float* conv_b     = (const float*)d_in[10];
  const float* W_att      = (const float*)d_in[11];
  const float* b_att      = (const float*)d_in[12];
  const float* W_out      = (const float*)d_in[13];
  const float* b_out      = (const float*)d_in[14];
  const float* W_int      = (const float*)d_in[15];
  const float* b_int      = (const float*)d_in[16];
  float* out = (float*)d_out;

  char* ws = (char*)d_ws;
  const size_t ps_bytes = (size_t)BB * LL * DD * 2;   // 64 MB each
  float*    compound  = (float*)ws;                                   // 64 KB
  uint16_t* ps_a      = (uint16_t*)(ws + 65536);
  uint16_t* ps_b      = (uint16_t*)(ws + 65536 + ps_bytes);
  uint16_t* btab      = (uint16_t*)(ws + 65536 + 2 * ps_bytes);       // 90 KB
  float*    hvec_g    = (float*)(ws + 65536 + 2 * ps_bytes + 131072); // 64 KB
  // pacc/msum alias ps_a: dead after conv layer 2 reads it; attn_part (sole
  // writer) is ordered after conv2.
  float*    pacc_part = (float*)ps_a;                                 // 2 MB
  float*    msum_part = (float*)((char*)ps_a + (size_t)BB * ACH * 4 * 64 * 4);

  bfrag_kernel<<<3, 64, 0, stream>>>(conv_k, btab);
  gnn_kernel<<<BB, 1024, 0, stream>>>(atoms, atoms_mask, adjacency, emb_fp,
                                      W_gnn, b_gnn, W_att, b_att,
                                      compound, hvec_g);
  gather_kernel<<<(BB * LL * DD / 8) / 256, 256, 0, stream>>>(amino, emb_word, ps_a);
  conv_mfma_kernel<<<dim3(LL / 64, BB), 256, 0, stream>>>(ps_a, ps_b, btab, conv_b, 0);
  conv_mfma_kernel<<<dim3(LL / 64, BB), 256, 0, stream>>>(ps_b, ps_a, btab, conv_b, 1);
  conv_mfma_kernel<<<dim3(LL / 64, BB), 256, 0, stream>>>(ps_a, ps_b, btab, conv_b, 2);
  attn_part_kernel<<<dim3(ACH, BB), 256, 0, stream>>>(ps_b, amino_mask, hvec_g,
                                                      W_att, b_att,
                                                      pacc_part, msum_part);
  attn_final_kernel<<<BB, 128, 0, stream>>>(compound, pacc_part, msum_part,
                                            W_out, b_out, W_int, b_int, out);
}

// Round 5
// 469.007 us; speedup vs baseline: 3.1956x; 1.1620x over previous
//
#include <hip/hip_runtime.h>
#include <hip/hip_bf16.h>
#include <cstdint>
#include <cstddef>

#define BB 256
#define NN 128
#define LL 2048
#define DD 64
#define KS 23
#define PAD 11
#define EPSF 1e-6f
#define ACH 8    // attention L-chunks: block covers 256 rows

typedef __bf16 v8bf __attribute__((ext_vector_type(8)));
typedef float v4f __attribute__((ext_vector_type(4)));

__device__ __forceinline__ float bf2f(uint32_t u) {
  union { uint32_t i; float f; } c; c.i = u << 16; return c.f;
}
__device__ __forceinline__ uint16_t f2bf(float f) {
  union { float f; uint32_t i; } c; c.f = f;
  uint32_t i = c.i;
  return (uint16_t)((i + 0x7fffu + ((i >> 16) & 1u)) >> 16);
}
__device__ __forceinline__ __bf16 f2bf16(float f) {
  union { uint16_t u; __bf16 h; } c; c.u = f2bf(f); return c.h;
}
__device__ __forceinline__ v8bf cvt8(float4 f0, float4 f1) {
  v8bf r;
  r[0] = (__bf16)f0.x; r[1] = (__bf16)f0.y; r[2] = (__bf16)f0.z; r[3] = (__bf16)f0.w;
  r[4] = (__bf16)f1.x; r[5] = (__bf16)f1.y; r[6] = (__bf16)f1.z; r[7] = (__bf16)f1.w;
  return r;
}

// ----------------------------------------------------------- GNN (MFMA) ----
// One block per b, 256 threads = 4 waves; wave w owns atom rows [32w,32w+32).
// Per layer: hs = relu(xs@W^T + b) via mfma (A = xs fp32->bf16 from LDS,
// B = W_gnn bf16 from global); hsT (bf16, transposed) in LDS; then
// xs += adj@hs via mfma (A = adj fp32->bf16 straight from global, prefetched;
// B = hsT b128 reads; C init = old xs). xs rows are wave-private => only the
// hsT WAR/RAW barriers are needed (2 per layer).
#define XSS 68    // xs row stride (words): 16B-aligned rows, 2-way banks
#define HTS3 136  // hsT row stride (halves)

__global__ __launch_bounds__(256) void gnn_kernel(
    const int* __restrict__ atoms, const float* __restrict__ atoms_mask,
    const float* __restrict__ adj, const float* __restrict__ emb_fp,
    const float* __restrict__ W_gnn, const float* __restrict__ b_gnn,
    const float* __restrict__ W_att, const float* __restrict__ b_att,
    float* __restrict__ compound, float* __restrict__ hvec_g)
{
  __shared__ float xs[NN * XSS];
  __shared__ uint16_t hsT[DD * HTS3];
  __shared__ float mask_s[NN];
  __shared__ float psum[4][64];
  __shared__ float cvec[64];

  const int b = blockIdx.x;
  const int tid = threadIdx.x;
  const int lane = tid & 63;
  const int w = tid >> 6;         // 0..3
  const int m16 = lane & 15;
  const int s = lane >> 4;        // 0..3

  // stage xs = emb_fp[atoms[b]] (fp32) + atom mask
  for (int idx = tid; idx < NN * 16; idx += 256) {
    int n = idx >> 4, c4 = idx & 15;
    int a = atoms[b * NN + n];
    float4 v = ((const float4*)(emb_fp + (size_t)a * DD))[c4];
    *(float4*)(xs + n * XSS + c4 * 4) = v;
  }
  if (tid < NN) mask_s[tid] = atoms_mask[b * NN + tid];
  __syncthreads();

  const int row0 = 32 * w;
  for (int layer = 0; layer < 3; ++layer) {
    // W_gnn B-frags + bias (global, L2-hot)
    v8bf Wf[2][4];
    float bias[4];
    const float* Wl = W_gnn + (size_t)layer * DD * DD;
    #pragma unroll
    for (int nt = 0; nt < 4; ++nt) {
      bias[nt] = b_gnn[layer * DD + nt * 16 + m16];
      #pragma unroll
      for (int kc = 0; kc < 2; ++kc) {
        const float* p = Wl + (size_t)(nt * 16 + m16) * DD + kc * 32 + s * 8;
        Wf[kc][nt] = cvt8(((const float4*)p)[0], ((const float4*)p)[1]);
      }
    }
    // prefetch this wave's adjacency A-frags (raw fp32) — overlaps hs GEMM
    float4 araw[8][2];
    const float* adjw = adj + ((size_t)b * NN + row0) * NN;
    #pragma unroll
    for (int kc = 0; kc < 4; ++kc)
      #pragma unroll
      for (int mt = 0; mt < 2; ++mt) {
        const float* p = adjw + (size_t)(mt * 16 + m16) * NN + kc * 32 + s * 8;
        araw[kc * 2 + mt][0] = ((const float4*)p)[0];
        araw[kc * 2 + mt][1] = ((const float4*)p)[1];
      }

    // hs GEMM: M=32 (2 mt), N=64 (4 nt), K=64 (2 kc)
    v4f acc[2][4];
    #pragma unroll
    for (int mt = 0; mt < 2; ++mt)
      #pragma unroll
      for (int nt = 0; nt < 4; ++nt)
        acc[mt][nt] = (v4f){bias[nt], bias[nt], bias[nt], bias[nt]};
    #pragma unroll
    for (int kc = 0; kc < 2; ++kc) {
      v8bf Axs[2];
      #pragma unroll
      for (int mt = 0; mt < 2; ++mt) {
        const float* p = xs + (size_t)(row0 + mt * 16 + m16) * XSS + kc * 32 + s * 8;
        Axs[mt] = cvt8(((const float4*)p)[0], ((const float4*)p)[1]);
      }
      #pragma unroll
      for (int mt = 0; mt < 2; ++mt)
        #pragma unroll
        for (int nt = 0; nt < 4; ++nt)
          acc[mt][nt] = __builtin_amdgcn_mfma_f32_16x16x32_bf16(
              Axs[mt], Wf[kc][nt], acc[mt][nt], 0, 0, 0);
    }
    __syncthreads();   // WAR: prior layer's hsT reads done before overwrite
    // write hsT[e][m] = relu(hs) (bf16), m in this wave's rows
    #pragma unroll
    for (int mt = 0; mt < 2; ++mt)
      #pragma unroll
      for (int nt = 0; nt < 4; ++nt) {
        int e = nt * 16 + m16;
        int m = row0 + mt * 16 + s * 4;
        union { uint64_t u; __bf16 h[4]; } pk;
        #pragma unroll
        for (int r = 0; r < 4; ++r)
          pk.h[r] = (__bf16)fmaxf(acc[mt][nt][r], 0.f);
        *(uint64_t*)(hsT + (size_t)e * HTS3 + m) = pk.u;
      }
    __syncthreads();   // RAW: hsT complete before B-frag reads

    // adj GEMM: M=32, N=64, K=128 (4 kc); C init = old xs
    v4f acc2[2][4];
    #pragma unroll
    for (int mt = 0; mt < 2; ++mt)
      #pragma unroll
      for (int nt = 0; nt < 4; ++nt)
        #pragma unroll
        for (int r = 0; r < 4; ++r)
          acc2[mt][nt][r] = xs[(size_t)(row0 + mt * 16 + s * 4 + r) * XSS + nt * 16 + m16];
    #pragma unroll
    for (int kc = 0; kc < 4; ++kc) {
      v8bf Aa[2];
      #pragma unroll
      for (int mt = 0; mt < 2; ++mt)
        Aa[mt] = cvt8(araw[kc * 2 + mt][0], araw[kc * 2 + mt][1]);
      v8bf Bh[4];
      #pragma unroll
      for (int nt = 0; nt < 4; ++nt)
        Bh[nt] = *(const v8bf*)(hsT + (size_t)(nt * 16 + m16) * HTS3 + kc * 32 + s * 8);
      #pragma unroll
      for (int mt = 0; mt < 2; ++mt)
        #pragma unroll
        for (int nt = 0; nt < 4; ++nt)
          acc2[mt][nt] = __builtin_amdgcn_mfma_f32_16x16x32_bf16(
              Aa[mt], Bh[nt], acc2[mt][nt], 0, 0, 0);
    }
    // write xs back (wave-private rows => no barrier)
    #pragma unroll
    for (int mt = 0; mt < 2; ++mt)
      #pragma unroll
      for (int nt = 0; nt < 4; ++nt)
        #pragma unroll
        for (int r = 0; r < 4; ++r)
          xs[(size_t)(row0 + mt * 16 + s * 4 + r) * XSS + nt * 16 + m16] = acc2[mt][nt][r];
  }

  // masked-mean epilogue: per-wave partial over own rows (no barrier needed)
  float pr = 0.f;
  for (int i = 0; i < 32; ++i) {
    int n = row0 + i;
    pr = fmaf(mask_s[n], xs[(size_t)n * XSS + lane], pr);
  }
  psum[w][lane] = pr;
  __syncthreads();
  if (tid < 64) {
    float ssum = psum[0][tid] + psum[1][tid] + psum[2][tid] + psum[3][tid];
    float den = 0.f;
    #pragma unroll 8
    for (int i = 0; i < NN; ++i) den += mask_s[i];
    float c = ssum / (den + EPSF);
    compound[b * DD + tid] = c;
    cvec[tid] = c;
  }
  __syncthreads();
  if (tid < 64) {
    float a = b_att[tid];
    const float* wr = W_att + (size_t)tid * DD;
    #pragma unroll
    for (int d4 = 0; d4 < 16; ++d4) {
      float4 w4 = ((const float4*)wr)[d4];
      float4 c4 = ((const float4*)cvec)[d4];
      a = fmaf(w4.x, c4.x, a); a = fmaf(w4.y, c4.y, a);
      a = fmaf(w4.z, c4.z, a); a = fmaf(w4.w, c4.w, a);
    }
    hvec_g[b * DD + tid] = fmaxf(a, 0.f);
  }
}

// ------------------------------------------------------------- gather ------
__global__ __launch_bounds__(256) void gather_kernel(
    const int* __restrict__ amino, const float* __restrict__ emb_word,
    uint16_t* __restrict__ ps)
{
  int gid = blockIdx.x * 256 + threadIdx.x;
  int row = gid >> 3, c8 = gid & 7;
  int a = amino[row];
  const float* src = emb_word + (size_t)a * DD + c8 * 8;
  float4 f0 = ((const float4*)src)[0];
  float4 f1 = ((const float4*)src)[1];
  union { uint4 u; uint16_t h[8]; } pk;
  pk.h[0] = f2bf(f0.x); pk.h[1] = f2bf(f0.y);
  pk.h[2] = f2bf(f0.z); pk.h[3] = f2bf(f0.w);
  pk.h[4] = f2bf(f1.x); pk.h[5] = f2bf(f1.y);
  pk.h[6] = f2bf(f1.z); pk.h[7] = f2bf(f1.w);
  *(uint4*)(ps + (size_t)row * DD + c8 * 8) = pk.u;
}

// -------------------------------------------- B-fragment table precompute --
__global__ __launch_bounds__(64) void bfrag_kernel(
    const float* __restrict__ conv_k, uint16_t* __restrict__ btab)
{
  const int layer = blockIdx.x;
  const int lane = threadIdx.x;
  const int s = lane >> 4, n = lane & 15;
  for (int kk = 0; kk < 30; ++kk) {
    int k8 = kk * 4 + s;
    int i = k8 / 5;
    int c8 = k8 - i * 5;
    #pragma unroll
    for (int j = 0; j < 8; ++j) {
      int c = c8 * 8 + j;
      int jj = c - n;
      float v = (i < KS && jj >= 0 && jj < KS)
                    ? conv_k[layer * KS * KS + i * KS + jj] : 0.f;
      btab[(((size_t)layer * 30 + kk) * 64 + lane) * 8 + j] = f2bf(v);
    }
  }
}

// ----------------------------------------------------------- conv (MFMA) ---
#define TW 88
#define TR 88

__global__ __launch_bounds__(256, 2) void conv_mfma_kernel(
    const uint16_t* __restrict__ in, uint16_t* __restrict__ out,
    const uint16_t* __restrict__ btab, const float* __restrict__ conv_b,
    int layer)
{
  __shared__ uint16_t tile[TR * TW];
  const int tid = threadIdx.x;
  const int l0 = blockIdx.x * 64;
  const int b  = blockIdx.y;
  const int lane = tid & 63;
  const int g = tid >> 6;

  v8bf bfr[30];
  const uint16_t* bt = btab + (size_t)layer * 30 * 512 + lane * 8;
  #pragma unroll
  for (int kk = 0; kk < 30; ++kk)
    bfr[kk] = *(const v8bf*)(bt + kk * 512);

  for (int i = tid; i < TR * TW / 8; i += 256)
    ((uint4*)tile)[i] = make_uint4(0u, 0u, 0u, 0u);
  __syncthreads();
  const uint16_t* inb = in + (size_t)b * LL * DD;
  for (int idx = tid; idx < 86 * 8; idx += 256) {
    int t = idx >> 3, c8 = idx & 7;
    int gl = l0 - PAD + t;
    if (gl >= 0 && gl < LL) {
      uint4 v = *(const uint4*)(inb + (size_t)gl * DD + c8 * 8);
      uint16_t* dst = tile + t * TW + PAD + c8 * 8;
      dst[0] = (uint16_t)(v.x & 0xffffu); dst[1] = (uint16_t)(v.x >> 16);
      dst[2] = (uint16_t)(v.y & 0xffffu); dst[3] = (uint16_t)(v.y >> 16);
      dst[4] = (uint16_t)(v.z & 0xffffu); dst[5] = (uint16_t)(v.z >> 16);
      dst[6] = (uint16_t)(v.w & 0xffffu); dst[7] = (uint16_t)(v.w >> 16);
    }
  }
  __syncthreads();

  const int s = lane >> 4;
  const int m16 = lane & 15;
  v4f acc[4];
  #pragma unroll
  for (int m = 0; m < 4; ++m) acc[m] = (v4f){0.f, 0.f, 0.f, 0.f};

  #pragma unroll
  for (int kk = 0; kk < 30; ++kk) {
    int k8 = kk * 4 + s;
    int i = k8 / 5;
    int c8 = k8 - i * 5;
    const uint16_t* ap = tile + (m16 + i) * TW + 16 * g + c8 * 8;
    v8bf a0 = *(const v8bf*)(ap);
    v8bf a1 = *(const v8bf*)(ap + 16 * TW);
    v8bf a2 = *(const v8bf*)(ap + 32 * TW);
    v8bf a3 = *(const v8bf*)(ap + 48 * TW);
    acc[0] = __builtin_amdgcn_mfma_f32_16x16x32_bf16(a0, bfr[kk], acc[0], 0, 0, 0);
    acc[1] = __builtin_amdgcn_mfma_f32_16x16x32_bf16(a1, bfr[kk], acc[1], 0, 0, 0);
    acc[2] = __builtin_amdgcn_mfma_f32_16x16x32_bf16(a2, bfr[kk], acc[2], 0, 0, 0);
    acc[3] = __builtin_amdgcn_mfma_f32_16x16x32_bf16(a3, bfr[kk], acc[3], 0, 0, 0);
  }

  const float bias = conv_b[layer];
  uint16_t* outb = out + ((size_t)b * LL + l0) * DD + 16 * g + m16;
  #pragma unroll
  for (int m = 0; m < 4; ++m) {
    #pragma unroll
    for (int r = 0; r < 4; ++r) {
      int row = m * 16 + s * 4 + r;
      outb[(size_t)row * DD] = f2bf(fmaxf(acc[m][r] + bias, 0.f));
    }
  }
}

// --------------------------------------------- attention partials (MFMA) ---
#define HTS2 66

__global__ __launch_bounds__(256) void attn_part_kernel(
    const uint16_t* __restrict__ ps, const float* __restrict__ amino_mask,
    const float* __restrict__ hvec_g, const float* __restrict__ W_att,
    const float* __restrict__ b_att, float* __restrict__ pacc_part,
    float* __restrict__ msum_part)
{
  __shared__ float ht[4][32 * HTS2];
  __shared__ float pm_s[4][64];
  __shared__ float wv_s[4][32];
  __shared__ float hv_s[64];

  const int chunk = blockIdx.x;
  const int b = blockIdx.y;
  const int tid = threadIdx.x;
  const int lane = tid & 63;
  const int w = tid >> 6;
  const int m16 = lane & 15;
  const int s = lane >> 4;

  v8bf bfrB[2][4];
  float bias[4];
  #pragma unroll
  for (int nt = 0; nt < 4; ++nt) {
    bias[nt] = b_att[nt * 16 + m16];
    const float* wr = W_att + (size_t)(nt * 16 + m16) * DD + s * 8;
    #pragma unroll
    for (int kc = 0; kc < 2; ++kc) {
      float4 f0 = ((const float4*)(wr + kc * 32))[0];
      float4 f1 = ((const float4*)(wr + kc * 32))[1];
      bfrB[kc][nt] = cvt8(f0, f1);
    }
  }
  if (tid < 64) hv_s[tid] = hvec_g[b * DD + tid];

  const int rowbase = chunk * 256 + w * 64;
  const float* pmb = amino_mask + (size_t)b * LL;
  pm_s[w][lane] = pmb[rowbase + lane];
  const float macc = pm_s[w][lane];
  __syncthreads();

  float pacc[4] = {0.f, 0.f, 0.f, 0.f};
  const uint16_t* psb = ps + ((size_t)b * LL + rowbase) * DD;

  #pragma unroll
  for (int step = 0; step < 2; ++step) {
    const uint16_t* pr = psb + (size_t)step * 32 * DD;
    v8bf A[2][2];
    #pragma unroll
    for (int mt = 0; mt < 2; ++mt)
      #pragma unroll
      for (int kc = 0; kc < 2; ++kc)
        A[mt][kc] = *(const v8bf*)(pr + (mt * 16 + m16) * DD + kc * 32 + s * 8);

    v4f acc[2][4];
    #pragma unroll
    for (int mt = 0; mt < 2; ++mt)
      #pragma unroll
      for (int nt = 0; nt < 4; ++nt)
        acc[mt][nt] = (v4f){0.f, 0.f, 0.f, 0.f};
    #pragma unroll
    for (int kc = 0; kc < 2; ++kc)
      #pragma unroll
      for (int mt = 0; mt < 2; ++mt)
        #pragma unroll
        for (int nt = 0; nt < 4; ++nt)
          acc[mt][nt] = __builtin_amdgcn_mfma_f32_16x16x32_bf16(
              A[mt][kc], bfrB[kc][nt], acc[mt][nt], 0, 0, 0);

    float vals[2][4][4];
    float* htw = ht[w];
    #pragma unroll
    for (int mt = 0; mt < 2; ++mt)
      #pragma unroll
      for (int r = 0; r < 4; ++r) {
        int row = mt * 16 + s * 4 + r;
        float pm = pm_s[w][step * 32 + row];
        #pragma unroll
        for (int nt = 0; nt < 4; ++nt) {
          float v = fmaxf(acc[mt][nt][r] + bias[nt], 0.f) * pm;
          vals[mt][nt][r] = v;
          htw[row * HTS2 + nt * 16 + m16] = v;
        }
      }
    __syncthreads();

    {
      int row = lane & 31, eh = lane >> 5;
      const float* hr = ht[w] + row * HTS2 + eh * 32;
      const float* hv = hv_s + eh * 32;
      float d = 0.f;
      #pragma unroll
      for (int t = 0; t < 8; ++t) {
        float4 hh = *(const float4*)(hr + 4 * t);
        float4 vv = *(const float4*)(hv + 4 * t);
        d = fmaf(hh.x, vv.x, d); d = fmaf(hh.y, vv.y, d);
        d = fmaf(hh.z, vv.z, d); d = fmaf(hh.w, vv.w, d);
      }
      d += __shfl_xor(d, 32);
      float wt = tanhf(d);
      if (lane < 32) wv_s[w][row] = wt;
    }
    __syncthreads();

    #pragma unroll
    for (int mt = 0; mt < 2; ++mt)
      #pragma unroll
      for (int r = 0; r < 4; ++r) {
        float wt = wv_s[w][mt * 16 + s * 4 + r];
        #pragma unroll
        for (int nt = 0; nt < 4; ++nt)
          pacc[nt] = fmaf(wt, vals[mt][nt][r], pacc[nt]);
      }
    __syncthreads();
  }

  const size_t idx = ((size_t)b * ACH + chunk) * 4 + w;
  #pragma unroll
  for (int nt = 0; nt < 4; ++nt) {
    float p = pacc[nt];
    p += __shfl_xor(p, 16);
    p += __shfl_xor(p, 32);
    if (m16 == lane)
      pacc_part[idx * 64 + nt * 16 + lane] = p;
  }
  float m = macc;
  #pragma unroll
  for (int off = 1; off < 64; off <<= 1) m += __shfl_xor(m, off);
  if (lane == 0) msum_part[idx] = m;
}

// --------------------------------------------------- finalize + FC head ----
__global__ __launch_bounds__(128) void attn_final_kernel(
    const float* __restrict__ compound, const float* __restrict__ pacc_part,
    const float* __restrict__ msum_part, const float* __restrict__ W_out,
    const float* __restrict__ b_out, const float* __restrict__ W_int,
    const float* __restrict__ b_int, float* __restrict__ outp)
{
  __shared__ float cat[128];
  __shared__ float cat2[128];
  const int b = blockIdx.x;
  const int tid = threadIdx.x;

  if (tid < 64) {
    float p = 0.f, den = 0.f;
    #pragma unroll 4
    for (int c = 0; c < ACH * 4; ++c) {
      p += pacc_part[((size_t)b * ACH * 4 + c) * 64 + tid];
      den += msum_part[b * ACH * 4 + c];
    }
    cat[tid] = compound[b * DD + tid];
    cat[64 + tid] = p / (den + EPSF);
  }
  __syncthreads();
  {
    float a = b_out[tid];
    const float* wr = W_out + (size_t)tid * 128;
    #pragma unroll 8
    for (int dd = 0; dd < 128; ++dd) a = fmaf(wr[dd], cat[dd], a);
    cat2[tid] = fmaxf(a, 0.f);
  }
  __syncthreads();
  {
    float a = b_out[128 + tid];
    const float* wr = W_out + 128 * 128 + (size_t)tid * 128;
    #pragma unroll 8
    for (int dd = 0; dd < 128; ++dd) a = fmaf(wr[dd], cat2[dd], a);
    __syncthreads();
    cat[tid] = fmaxf(a, 0.f);
  }
  __syncthreads();
  if (tid < 2) {
    float a = b_int[tid];
    const float* wr = W_int + (size_t)tid * 128;
    #pragma unroll 8
    for (int dd = 0; dd < 128; ++dd) a = fmaf(wr[dd], cat[dd], a);
    outp[b * 2 + tid] = a;
  }
}

// -------------------------------------------------------------- launch -----
extern "C" void kernel_launch(void* const* d_in, const int* in_sizes, int n_in,
                              void* d_out, int out_size, void* d_ws, size_t ws_size,
                              hipStream_t stream) {
  const int*   atoms      = (const int*)d_in[0];
  const float* atoms_mask = (const float*)d_in[1];
  const float* adjacency  = (const float*)d_in[2];
  const int*   amino      = (const int*)d_in[3];
  const float* amino_mask = (const float*)d_in[4];
  const float* emb_fp     = (const float*)d_in[5];
  const float* emb_word   = (const float*)d_in[6];
  const float* W_gnn      = (const float*)d_in[7];
  const float* b_gnn      = (const float*)d_in[8];
  const float* conv_k     = (const float*)d_in[9];
  const float* conv_b     = (const float*)d_in[10];
  const float* W_att      = (const float*)d_in[11];
  const float* b_att      = (const float*)d_in[12];
  const float* W_out      = (const float*)d_in[13];
  const float* b_out      = (const float*)d_in[14];
  const float* W_int      = (const float*)d_in[15];
  const float* b_int      = (const float*)d_in[16];
  float* out = (float*)d_out;

  char* ws = (char*)d_ws;
  const size_t ps_bytes = (size_t)BB * LL * DD * 2;   // 64 MB each
  float*    compound  = (float*)ws;                                   // 64 KB
  uint16_t* ps_a      = (uint16_t*)(ws + 65536);
  uint16_t* ps_b      = (uint16_t*)(ws + 65536 + ps_bytes);
  uint16_t* btab      = (uint16_t*)(ws + 65536 + 2 * ps_bytes);       // 90 KB
  float*    hvec_g    = (float*)(ws + 65536 + 2 * ps_bytes + 131072); // 64 KB
  // pacc/msum alias ps_a: dead after conv layer 2 reads it; attn_part (sole
  // writer) is ordered after conv2.
  float*    pacc_part = (float*)ps_a;                                 // 2 MB
  float*    msum_part = (float*)((char*)ps_a + (size_t)BB * ACH * 4 * 64 * 4);

  bfrag_kernel<<<3, 64, 0, stream>>>(conv_k, btab);
  gnn_kernel<<<BB, 256, 0, stream>>>(atoms, atoms_mask, adjacency, emb_fp,
                                     W_gnn, b_gnn, W_att, b_att,
                                     compound, hvec_g);
  gather_kernel<<<(BB * LL * DD / 8) / 256, 256, 0, stream>>>(amino, emb_word, ps_a);
  conv_mfma_kernel<<<dim3(LL / 64, BB), 256, 0, stream>>>(ps_a, ps_b, btab, conv_b, 0);
  conv_mfma_kernel<<<dim3(LL / 64, BB), 256, 0, stream>>>(ps_b, ps_a, btab, conv_b, 1);
  conv_mfma_kernel<<<dim3(LL / 64, BB), 256, 0, stream>>>(ps_a, ps_b, btab, conv_b, 2);
  attn_part_kernel<<<dim3(ACH, BB), 256, 0, stream>>>(ps_b, amino_mask, hvec_g,
                                                      W_att, b_att,
                                                      pacc_part, msum_part);
  attn_final_kernel<<<BB, 128, 0, stream>>>(compound, pacc_part, msum_part,
                                            W_out, b_out, W_int, b_int, out);
}